// Round 8
// baseline (380.436 us; speedup 1.0000x reference)
//
#include <hip/hip_runtime.h>
#include <hip/hip_bf16.h>

#define N_NODES 100000
#define E_EDGES 1600000
#define ETOT    1700000   // E + N self-loops
#define NB_SCAN 391       // ceil(N/256)
#define EQ4     400000    // E_EDGES / 4
#define NB_EQ4  1563      // ceil(EQ4 / 256)
#define F_IN    128
#define HC      64
#define OUT_C   40
#define NEG_SLOPE 0.2f
#define BN_EPS  1e-5f

// fp32 param block layout (element offsets)
#define P_W1   0
#define P_AS1  8192
#define P_AD1  8256
#define P_B1   8320
#define P_BNG  8384
#define P_BNB  8448
#define P_BNM  8512
#define P_BNV  8576
#define P_W2   8640
#define P_AS2  12736
#define P_AD2  12800
#define P_B2   12864
#define P_WF   12928
#define P_BF   15488
#define P_TOT  15528

typedef __attribute__((ext_vector_type(8))) short short8;
typedef __attribute__((ext_vector_type(4))) float floatx4;
typedef __attribute__((ext_vector_type(4))) unsigned int uintx4;

__device__ __forceinline__ unsigned short f2bf(float f) {   // RNE fp32->bf16
    unsigned int u = __float_as_uint(f);
    unsigned int r = u + 0x7FFFu + ((u >> 16) & 1u);
    return (unsigned short)(r >> 16);
}

// ---------------- dtype detection ----------------
__global__ __launch_bounds__(64) void detect_kernel(const unsigned short* __restrict__ x,
                                                    int* __restrict__ flag) {
    int t = threadIdx.x;
    bool huge = false;
#pragma unroll
    for (int i = 0; i < 4; ++i) {
        unsigned short u = x[(t * 4 + i) * 2];
        float v = __uint_as_float(((unsigned int)u) << 16);
        if (!(fabsf(v) < 1e4f)) huge = true;
    }
    unsigned long long b = __ballot(huge);
    if (t == 0) *flag = (b != 0ull) ? 1 : 0;             // 1 => fp32 tensors
}

// ---------------- small-param conversion to fp32 ----------------
struct CvtArgs { const void* ptr[14]; int len[14]; };

__global__ __launch_bounds__(256) void cvt_params_kernel(CvtArgs a,
                                                         const int* __restrict__ flag,
                                                         float* __restrict__ dst) {
    int f = *flag;
    int i = blockIdx.x * 256 + threadIdx.x;
    if (i >= P_TOT) return;
    int k = 0, off = 0;
    while (i >= off + a.len[k]) { off += a.len[k]; ++k; }
    int j = i - off;
    float v = f ? ((const float*)a.ptr[k])[j]
                : __bfloat162float(((const __hip_bfloat16*)a.ptr[k])[j]);
    dst[i] = v;
}

// ---------------- W1/W2 -> bf16 MFMA B-fragment order ----------------
__global__ __launch_bounds__(256) void build_frags_kernel(const float* __restrict__ prm,
                                                          unsigned short* __restrict__ fw1,
                                                          unsigned short* __restrict__ fw2) {
    int i = blockIdx.x * 256 + threadIdx.x;
    if (i < 8192) {
        int j = i & 7, l = (i >> 3) & 63, q = (i >> 9) & 3, t = i >> 11;
        int k = q * 32 + (l >> 4) * 8 + j;
        int n = t * 16 + (l & 15);
        fw1[i] = f2bf(prm[P_W1 + k * 64 + n]);
    } else if (i < 12288) {
        int f = i - 8192;
        int j = f & 7, l = (f >> 3) & 63, q = (f >> 9) & 1, t = f >> 10;
        int k = q * 32 + (l >> 4) * 8 + j;
        int n = t * 16 + (l & 15);
        fw2[f] = f2bf(prm[P_W2 + k * 64 + n]);
    }
}

// ---------------- CSR build, R12 (confirmed win): rank-based, atomic-free ----------------
__global__ __launch_bounds__(256) void histrank_kernel(const int* __restrict__ ei,
                                                       int* __restrict__ deg,
                                                       int4* __restrict__ rank4) {
    int i4 = blockIdx.x * 256 + threadIdx.x;
    if (i4 >= EQ4) return;
    const unsigned long long* dst2 = (const unsigned long long*)(ei + E_EDGES);
    unsigned long long p0 = __builtin_nontemporal_load(&dst2[i4 * 2]);
    unsigned long long p1 = __builtin_nontemporal_load(&dst2[i4 * 2 + 1]);
    int d0 = (int)(p0 & 0xFFFFFFFFull), d1 = (int)(p0 >> 32);
    int d2 = (int)(p1 & 0xFFFFFFFFull), d3 = (int)(p1 >> 32);
    int4 r;
    r.x = atomicAdd(&deg[d0], 1);     // 4 independent atomics, all in flight
    r.y = atomicAdd(&deg[d1], 1);
    r.z = atomicAdd(&deg[d2], 1);
    r.w = atomicAdd(&deg[d3], 1);
    rank4[i4] = r;                    // coalesced 16B store
}

// parallel scan; degree counted as deg[i]+1 (self-loop folded in)
__global__ __launch_bounds__(256) void scanA_kernel(const int* __restrict__ deg,
                                                    int* __restrict__ bsum) {
    __shared__ int sm[256];
    int t = threadIdx.x;
    int i = blockIdx.x * 256 + t;
    sm[t] = (i < N_NODES) ? deg[i] + 1 : 0;
    __syncthreads();
    for (int off = 128; off > 0; off >>= 1) {
        if (t < off) sm[t] += sm[t + off];
        __syncthreads();
    }
    if (t == 0) bsum[blockIdx.x] = sm[0];
}

__global__ __launch_bounds__(512) void scanB_kernel(const int* __restrict__ bsum,
                                                    int* __restrict__ boff,
                                                    int* __restrict__ row_start) {
    __shared__ int sm[512];
    int t = threadIdx.x;
    int v = (t < NB_SCAN) ? bsum[t] : 0;
    sm[t] = v;
    __syncthreads();
    for (int off = 1; off < 512; off <<= 1) {
        int o = (t >= off) ? sm[t - off] : 0;
        __syncthreads();
        sm[t] += o;
        __syncthreads();
    }
    if (t < NB_SCAN) boff[t] = sm[t] - v;
    if (t == NB_SCAN - 1) row_start[N_NODES] = sm[t];   // == ETOT
}

__global__ __launch_bounds__(256) void scanC_kernel(const int* __restrict__ deg,
                                                    const int* __restrict__ boff,
                                                    int* __restrict__ row_start,
                                                    int* __restrict__ col) {
    __shared__ int sm[256];
    int t = threadIdx.x;
    int i = blockIdx.x * 256 + t;
    int v = (i < N_NODES) ? deg[i] + 1 : 0;
    sm[t] = v;
    __syncthreads();
    for (int off = 1; off < 256; off <<= 1) {
        int o = (t >= off) ? sm[t - off] : 0;
        __syncthreads();
        sm[t] += o;
        __syncthreads();
    }
    if (i < N_NODES) {
        int excl = sm[t] - v + boff[blockIdx.x];
        row_start[i] = excl;
        col[excl]    = i;              // slot 0 = self-loop
    }
}

// ---------------- atomic-free scatter: pure stream + independent stores ----------------
__global__ __launch_bounds__(256) void scatter_kernel(const int* __restrict__ ei,
                                                      const int4* __restrict__ rank4,
                                                      const int* __restrict__ row_start,
                                                      int* __restrict__ col) {
    int i4 = blockIdx.x * 256 + threadIdx.x;
    if (i4 >= EQ4) return;
    const unsigned long long* dst2 = (const unsigned long long*)(ei + E_EDGES);
    const unsigned long long* src2 = (const unsigned long long*)ei;
    unsigned long long p0 = __builtin_nontemporal_load(&dst2[i4 * 2]);
    unsigned long long p1 = __builtin_nontemporal_load(&dst2[i4 * 2 + 1]);
    unsigned long long q0 = __builtin_nontemporal_load(&src2[i4 * 2]);
    unsigned long long q1 = __builtin_nontemporal_load(&src2[i4 * 2 + 1]);
    int4 r = rank4[i4];
    int d0 = (int)(p0 & 0xFFFFFFFFull), d1 = (int)(p0 >> 32);
    int d2 = (int)(p1 & 0xFFFFFFFFull), d3 = (int)(p1 >> 32);
    int s0 = (int)(q0 & 0xFFFFFFFFull), s1 = (int)(q0 >> 32);
    int s2 = (int)(q1 & 0xFFFFFFFFull), s3 = (int)(q1 >> 32);
    int b0 = row_start[d0];            // 4 independent gathers (L2-resident)
    int b1 = row_start[d1];
    int b2 = row_start[d2];
    int b3 = row_start[d3];
    col[b0 + 1 + r.x] = s0;            // 4 independent stores, no round-trip
    col[b1 + 1 + r.y] = s1;
    col[b2 + 1 + r.z] = s2;
    col[b3 + 1 + r.w] = s3;
}

__device__ __forceinline__ float leaky(float v) { return v > 0.f ? v : NEG_SLOPE * v; }

__device__ __forceinline__ float red64(float v) {
#pragma unroll
    for (int off = 32; off > 0; off >>= 1) v += __shfl_xor(v, off, 64);
    return v;
}
__device__ __forceinline__ float red16(float v) {
#pragma unroll
    for (int off = 8; off > 0; off >>= 1) v += __shfl_xor(v, off, 64);
    return v;
}

// ---------------- MFMA GEMM 1: h_bf[N,64] = x[N,128] @ W1, + fused alpha ----------------
__global__ __launch_bounds__(128) void gemm1_kernel(const void* __restrict__ x,
                                                    const unsigned short* __restrict__ fw1,
                                                    const float* __restrict__ prm,
                                                    const int* __restrict__ flag,
                                                    unsigned short* __restrict__ h_bf,
                                                    float* __restrict__ as_,
                                                    float* __restrict__ ad_) {
    __shared__ short lx[2 * 4 * 64 * 8];   // 8 KB
    int t = threadIdx.x;
    int f = *flag;
    int base = blockIdx.x * 32;

#pragma unroll
    for (int i = 0; i < 4; ++i) {
        int cid = i * 128 + t;
        int m = cid >> 4, c = cid & 15;
        int q = c >> 2, g = c & 3;
        int loff = (((m >> 4) * 4 + q) * 64 + g * 16 + (m & 15)) * 8;
        short8 s;
        if (f) {
            const float4* p = (const float4*)((const float*)x + ((size_t)(base + m) << 7) + (c << 3));
            float4 u0 = p[0], u1 = p[1];
            s[0] = (short)f2bf(u0.x); s[1] = (short)f2bf(u0.y);
            s[2] = (short)f2bf(u0.z); s[3] = (short)f2bf(u0.w);
            s[4] = (short)f2bf(u1.x); s[5] = (short)f2bf(u1.y);
            s[6] = (short)f2bf(u1.z); s[7] = (short)f2bf(u1.w);
        } else {
            s = *(const short8*)((const unsigned short*)x + ((size_t)(base + m) << 7) + (c << 3));
        }
        *(short8*)&lx[loff] = s;
    }
    __syncthreads();

    int w = t >> 6, lane = t & 63;
    short8 a[4];
#pragma unroll
    for (int q = 0; q < 4; ++q) a[q] = *(short8*)&lx[((w * 4 + q) * 64 + lane) * 8];

    const short8* bw = (const short8*)fw1;
    floatx4 acc[4];
#pragma unroll
    for (int tt = 0; tt < 4; ++tt) acc[tt] = (floatx4){0.f, 0.f, 0.f, 0.f};
#pragma unroll
    for (int tt = 0; tt < 4; ++tt) {
#pragma unroll
        for (int q = 0; q < 4; ++q) {
            short8 b = bw[(tt * 4 + q) * 64 + lane];
            acc[tt] = __builtin_amdgcn_mfma_f32_16x16x32_bf16(a[q], b, acc[tt], 0, 0, 0);
        }
    }

    int cl = lane & 15, grp = lane >> 4;
#pragma unroll
    for (int tt = 0; tt < 4; ++tt) {
#pragma unroll
        for (int r = 0; r < 4; ++r) {
            int node = base + w * 16 + grp * 4 + r;
            h_bf[(size_t)node * 64 + tt * 16 + cl] = f2bf(acc[tt][r]);
        }
    }

    float as0 = prm[P_AS1 + 0  + cl], as1 = prm[P_AS1 + 16 + cl],
          as2 = prm[P_AS1 + 32 + cl], as3 = prm[P_AS1 + 48 + cl];
    float ad0 = prm[P_AD1 + 0  + cl], ad1 = prm[P_AD1 + 16 + cl],
          ad2 = prm[P_AD1 + 32 + cl], ad3 = prm[P_AD1 + 48 + cl];
#pragma unroll
    for (int r = 0; r < 4; ++r) {
        float sh0 = red16(acc[0][r] * as0 + acc[1][r] * as1);
        float sh1 = red16(acc[2][r] * as2 + acc[3][r] * as3);
        float dh0 = red16(acc[0][r] * ad0 + acc[1][r] * ad1);
        float dh1 = red16(acc[2][r] * ad2 + acc[3][r] * ad3);
        if (cl == 0) {
            int node = base + w * 16 + grp * 4 + r;
            as_[node * 2] = sh0;  as_[node * 2 + 1] = sh1;
            ad_[node * 2] = dh0;  ad_[node * 2 + 1] = dh1;
        }
    }
}

// ---------------- MFMA GEMM 2: h_bf = x1_bf[N,64] @ W2, + fused alpha ----------------
__global__ __launch_bounds__(128) void gemm2_kernel(const unsigned short* __restrict__ x1_bf,
                                                    const unsigned short* __restrict__ fw2,
                                                    const float* __restrict__ prm,
                                                    unsigned short* __restrict__ h_bf,
                                                    float* __restrict__ as_,
                                                    float* __restrict__ ad_) {
    __shared__ short lx[2 * 2 * 64 * 8];   // 4 KB
    int t = threadIdx.x;
    int base = blockIdx.x * 32;

#pragma unroll
    for (int i = 0; i < 2; ++i) {
        int cid = i * 128 + t;
        int m = cid >> 3, c = cid & 7;
        int q = c >> 2, g = c & 3;
        int loff = (((m >> 4) * 2 + q) * 64 + g * 16 + (m & 15)) * 8;
        short8 s = *(const short8*)(x1_bf + ((size_t)(base + m) << 6) + (c << 3));
        *(short8*)&lx[loff] = s;
    }
    __syncthreads();

    int w = t >> 6, lane = t & 63;
    short8 a[2];
#pragma unroll
    for (int q = 0; q < 2; ++q) a[q] = *(short8*)&lx[((w * 2 + q) * 64 + lane) * 8];

    const short8* bw = (const short8*)fw2;
    floatx4 acc[4];
#pragma unroll
    for (int tt = 0; tt < 4; ++tt) acc[tt] = (floatx4){0.f, 0.f, 0.f, 0.f};
#pragma unroll
    for (int tt = 0; tt < 4; ++tt) {
#pragma unroll
        for (int q = 0; q < 2; ++q) {
            short8 b = bw[(tt * 2 + q) * 64 + lane];
            acc[tt] = __builtin_amdgcn_mfma_f32_16x16x32_bf16(a[q], b, acc[tt], 0, 0, 0);
        }
    }

    int cl = lane & 15, grp = lane >> 4;
#pragma unroll
    for (int tt = 0; tt < 4; ++tt) {
#pragma unroll
        for (int r = 0; r < 4; ++r) {
            int node = base + w * 16 + grp * 4 + r;
            h_bf[(size_t)node * 64 + tt * 16 + cl] = f2bf(acc[tt][r]);
        }
    }

    float as0 = prm[P_AS2 + 0  + cl], as1 = prm[P_AS2 + 16 + cl],
          as2 = prm[P_AS2 + 32 + cl], as3 = prm[P_AS2 + 48 + cl];
    float ad0 = prm[P_AD2 + 0  + cl], ad1 = prm[P_AD2 + 16 + cl],
          ad2 = prm[P_AD2 + 32 + cl], ad3 = prm[P_AD2 + 48 + cl];
#pragma unroll
    for (int r = 0; r < 4; ++r) {
        float sh0 = red16(acc[0][r] * as0 + acc[1][r] * as1);
        float sh1 = red16(acc[2][r] * as2 + acc[3][r] * as3);
        float dh0 = red16(acc[0][r] * ad0 + acc[1][r] * ad1);
        float dh1 = red16(acc[2][r] * ad2 + acc[3][r] * ad3);
        if (cl == 0) {
            int node = base + w * 16 + grp * 4 + r;
            as_[node * 2] = sh0;  as_[node * 2 + 1] = sh1;
            ad_[node * 2] = dh0;  ad_[node * 2 + 1] = dh1;
        }
    }
}

// halving slot-reduction: lane ends with channel k=(lane&7) summed over its
// octet's 8 slots. 7 shfl + 14 sel + 7 add (vs 24/24/7 full butterfly).
// All shuffles convergent.
__device__ __forceinline__ float slot_reduce(float acc[8], int lane) {
    int slot = lane & 7;
    bool b2 = (slot & 4) != 0;
#pragma unroll
    for (int q = 0; q < 4; ++q) {
        float send = b2 ? acc[q] : acc[q + 4];
        float recv = __shfl_xor(send, 4, 64);
        acc[q] = (b2 ? acc[q + 4] : acc[q]) + recv;
    }
    bool b1 = (slot & 2) != 0;
#pragma unroll
    for (int q = 0; q < 2; ++q) {
        float send = b1 ? acc[q] : acc[q + 2];
        float recv = __shfl_xor(send, 2, 64);
        acc[q] = (b1 ? acc[q + 2] : acc[q]) + recv;
    }
    bool b0 = (slot & 1) != 0;
    float send = b0 ? acc[0] : acc[1];
    float recv = __shfl_xor(send, 1, 64);
    return (b0 ? acc[1] : acc[0]) + recv;
}

// ---------------- aggregation round batch, MLP-pinned ----------------
// R14: VGPR_Count has sat at 28 for five rounds -- hipcc minimizes registers
// and serializes the batched gathers into load->use pairs (each round = one
// exposed L2/L3 latency). Fix: after issuing all NK h_bf gathers + NK as_
// gathers, ONE empty asm marker takes every result as "+v" operand. No load
// can sink past it and all results must be live simultaneously => loads
// issue back-to-back, compiler emits one merged s_waitcnt. Single asm (not
// per-k: a per-k pin would let later loads sink past earlier pins). uintx4
// ext_vector maps to VReg_128 for the "v" constraint; all indexing is
// compile-time (rule: runtime-indexed ext_vector goes to scratch).
template<int NK>
__device__ __forceinline__ void agg_rounds(const unsigned short* __restrict__ hb,
                                           const float* __restrict__ as_,
                                           const int* __restrict__ col,
                                           int rs, int koff, int last,
                                           int slot, int hi, float advh,
                                           float acc[8], float& sw) {
    int ce[NK]; float av[NK]; uintx4 dv[NK];
#pragma unroll
    for (int k = 0; k < NK; ++k) {
        int e = rs + koff + k * 8 + slot;
        ce[k] = col[e < last ? e : last];     // clamped: always valid
    }
#pragma unroll
    for (int k = 0; k < NK; ++k)
        dv[k] = *(const uintx4*)(hb + ((size_t)ce[k] << 6));
#pragma unroll
    for (int k = 0; k < NK; ++k)
        av[k] = as_[ce[k] * 2 + hi];

    if constexpr (NK == 1) {
        asm volatile("" : "+v"(dv[0]), "+v"(av[0]));
    } else if constexpr (NK == 2) {
        asm volatile("" : "+v"(dv[0]), "+v"(dv[1]), "+v"(av[0]), "+v"(av[1]));
    } else if constexpr (NK == 3) {
        asm volatile("" : "+v"(dv[0]), "+v"(dv[1]), "+v"(dv[2]),
                          "+v"(av[0]), "+v"(av[1]), "+v"(av[2]));
    } else {
        asm volatile("" : "+v"(dv[0]), "+v"(dv[1]), "+v"(dv[2]), "+v"(dv[3]),
                          "+v"(av[0]), "+v"(av[1]), "+v"(av[2]), "+v"(av[3]));
    }

#pragma unroll
    for (int k = 0; k < NK; ++k) {
        int e = rs + koff + k * 8 + slot;
        float w = (e <= last) ? __expf(leaky(av[k] + advh)) : 0.f;
        sw += w;
#pragma unroll
        for (int q = 0; q < 4; ++q) {
            unsigned int dw = dv[k][q];
            acc[2 * q]     = fmaf(w, __uint_as_float(dw << 16),         acc[2 * q]);
            acc[2 * q + 1] = fmaf(w, __uint_as_float(dw & 0xFFFF0000u), acc[2 * q + 1]);
        }
    }
}

// ---------------- aggregation core, slot-parallel, degree-adaptive ----------------
// R10 (win): shuffle-free slot loads. R13: degree-adaptive tiers (wave-
// uniform branch). R14: MLP pin inside each tier (see agg_rounds).
__device__ __forceinline__ float agg_core(const unsigned short* __restrict__ h_bf,
                                          const float* __restrict__ as_,
                                          const float* __restrict__ ad_,
                                          const int* __restrict__ col,
                                          int v, int rs, int re, int lane) {
    int deg  = re - rs;
    int slot = lane & 7;
    int cg   = lane >> 3;        // channel group: my 8 channels = cg*8..cg*8+7
    int hi   = cg >> 2;          // head owning my channels
    if (deg <= 64) {
        float advh = ad_[v * 2 + hi];
        const unsigned short* hb = h_bf + (cg << 3);
        int last = re - 1;       // >= rs always (self-loop)
        float acc[8] = {0.f,0.f,0.f,0.f,0.f,0.f,0.f,0.f};
        float sw = 0.f;

        if (deg <= 8) {
            agg_rounds<1>(hb, as_, col, rs, 0, last, slot, hi, advh, acc, sw);
        } else if (deg <= 16) {
            agg_rounds<2>(hb, as_, col, rs, 0, last, slot, hi, advh, acc, sw);
        } else if (deg <= 24) {
            agg_rounds<3>(hb, as_, col, rs, 0, last, slot, hi, advh, acc, sw);
        } else {
            agg_rounds<4>(hb, as_, col, rs, 0, last, slot, hi, advh, acc, sw);
            if (deg > 32)
                agg_rounds<4>(hb, as_, col, rs, 32, last, slot, hi, advh, acc, sw);
        }

        // denominator: sum over the octet's 8 slots (3 convergent shuffles)
        sw += __shfl_xor(sw, 1, 64);
        sw += __shfl_xor(sw, 2, 64);
        sw += __shfl_xor(sw, 4, 64);
        float rdh = 1.f / (sw + 1e-16f);

        return slot_reduce(acc, lane) * rdh;
    } else {
        int head = lane >> 5;
        float adv0 = ad_[v * 2], adv1 = ad_[v * 2 + 1];
        float advh = head ? adv1 : adv0;
        float s0 = 0.f, s1 = 0.f;
        for (int e = rs + lane; e < re; e += 64) {
            int s = col[e];
            float2 av = *(const float2*)&as_[s * 2];
            s0 += __expf(leaky(av.x + adv0));
            s1 += __expf(leaky(av.y + adv1));
        }
        s0 = red64(s0); s1 = red64(s1);
        float rdh = 1.f / ((head ? s1 : s0) + 1e-16f);
        float a0 = 0.f;
        for (int e = rs; e < re; ++e) {
            int s = col[e];
            float w = __expf(leaky(as_[s * 2 + head] + advh));
            unsigned short u = h_bf[(size_t)s * 64 + lane];
            a0 = fmaf(w, __uint_as_float(((unsigned int)u) << 16), a0);
        }
        return a0 * rdh;
    }
}

// ---------------- aggregation layer 1 (+bias, BN eval, ELU) -> x1_bf ----------------
__global__ __launch_bounds__(256, 6) void agg1_kernel(const unsigned short* __restrict__ h_bf,
                                                   const float* __restrict__ as_,
                                                   const float* __restrict__ ad_,
                                                   const int* __restrict__ row_start,
                                                   const int* __restrict__ col,
                                                   const float* __restrict__ bias,
                                                   const float* __restrict__ bn_g,
                                                   const float* __restrict__ bn_b,
                                                   const float* __restrict__ bn_m,
                                                   const float* __restrict__ bn_v,
                                                   unsigned short* __restrict__ x1_bf) {
    int t = threadIdx.x, wid = t >> 6, lane = t & 63;
    int v = blockIdx.x * 4 + wid;
    int rs = row_start[v], re = row_start[v + 1];
    float acc = agg_core(h_bf, as_, ad_, col, v, rs, re, lane);
    float r = acc + bias[lane];
    float scale = bn_g[lane] * rsqrtf(bn_v[lane] + BN_EPS);
    r = (r - bn_m[lane]) * scale + bn_b[lane];
    r = r > 0.f ? r : expm1f(r);   // ELU
    x1_bf[(size_t)v * 64 + lane] = f2bf(r);
}

// ---------------- agg layer 2 + JK max + fused projection -> out [N,40] ----------------
__global__ __launch_bounds__(256, 6) void agg2_kernel(const unsigned short* __restrict__ h_bf,
                                                   const float* __restrict__ as_,
                                                   const float* __restrict__ ad_,
                                                   const int* __restrict__ row_start,
                                                   const int* __restrict__ col,
                                                   const float* __restrict__ prm,
                                                   const unsigned short* __restrict__ x1_bf,
                                                   const int* __restrict__ flag,
                                                   void* __restrict__ out) {
    __shared__ float Wfs[2560];      // Wf[c*40+o] natural layout: lanes o stride-1 -> conflict-free
    __shared__ float xsh[4][64];
    int t = threadIdx.x;
#pragma unroll
    for (int i = 0; i < 10; ++i) Wfs[i * 256 + t] = prm[P_WF + i * 256 + t];

    int wid = t >> 6, lane = t & 63;
    int v = blockIdx.x * 4 + wid;
    int rs = row_start[v], re = row_start[v + 1];
    float acc = agg_core(h_bf, as_, ad_, col, v, rs, re, lane);
    float x2 = acc + prm[P_B2 + lane];
    unsigned short u = x1_bf[(size_t)v * 64 + lane];
    float x1v = __uint_as_float(((unsigned int)u) << 16);
    xsh[wid][lane] = fmaxf(x1v, x2);   // JumpingKnowledge max
    __syncthreads();

    if (t < 160) {                     // 4 nodes x 40 outputs
        int n = t / 40, o = t - n * 40;
        float po = 0.f;
#pragma unroll
        for (int c = 0; c < 64; c += 4) {
            po = fmaf(xsh[n][c],     Wfs[c * 40 + o],       po);
            po = fmaf(xsh[n][c + 1], Wfs[(c + 1) * 40 + o], po);
            po = fmaf(xsh[n][c + 2], Wfs[(c + 2) * 40 + o], po);
            po = fmaf(xsh[n][c + 3], Wfs[(c + 3) * 40 + o], po);
        }
        float r = po + prm[P_BF + o];
        size_t idx = (size_t)(blockIdx.x * 4 + n) * 40 + o;
        if (*flag) ((float*)out)[idx] = r;
        else ((__hip_bfloat16*)out)[idx] = __float2bfloat16(r);
    }
}

extern "C" void kernel_launch(void* const* d_in, const int* in_sizes, int n_in,
                              void* d_out, int out_size, void* d_ws, size_t ws_size,
                              hipStream_t stream) {
    (void)in_sizes; (void)n_in; (void)out_size; (void)ws_size;
    const void* node_feat = d_in[0];
    const int*  edge_idx  = (const int*)d_in[1];

    char* ws = (char*)d_ws;
    size_t off = 0;
    auto alloc = [&](size_t bytes) -> void* {
        void* p = ws + off;
        off += (bytes + 255) & ~(size_t)255;
        return p;
    };
    unsigned short* h_bf  = (unsigned short*)alloc((size_t)N_NODES * 64 * 2);  // 12.8 MB
    unsigned short* x1_bf = (unsigned short*)alloc((size_t)N_NODES * 64 * 2);  // 12.8 MB
    float* as_ = (float*)alloc((size_t)N_NODES * 2 * 4);
    float* ad_ = (float*)alloc((size_t)N_NODES * 2 * 4);
    int* deg       = (int*)alloc((size_t)N_NODES * 4);
    int* row_start = (int*)alloc((size_t)(N_NODES + 1) * 4);
    int4* rank4    = (int4*)alloc((size_t)EQ4 * 16);        // 6.4 MB (32-bit ranks)
    int* col       = (int*)alloc((size_t)ETOT * 4);         // 6.8 MB
    int* bsum      = (int*)alloc((size_t)NB_SCAN * 4);
    int* boff      = (int*)alloc((size_t)NB_SCAN * 4);
    float* prm     = (float*)alloc((size_t)P_TOT * 4);
    unsigned short* fw1 = (unsigned short*)alloc(8192 * 2);
    unsigned short* fw2 = (unsigned short*)alloc(4096 * 2);
    int* flag      = (int*)alloc(256);

    detect_kernel<<<1, 64, 0, stream>>>((const unsigned short*)node_feat, flag);
    CvtArgs ca;
    const int lens[14] = {8192, 64, 64, 64, 64, 64, 64, 64, 4096, 64, 64, 64, 2560, 40};
    for (int i = 0; i < 14; ++i) { ca.ptr[i] = d_in[i + 2]; ca.len[i] = lens[i]; }
    cvt_params_kernel<<<(P_TOT + 255) / 256, 256, 0, stream>>>(ca, flag, prm);
    build_frags_kernel<<<48, 256, 0, stream>>>(prm, fw1, fw2);

    // CSR build: rank-based (R12). hist computes per-edge rank via atomic
    // return; scatter is atomic-free.
    hipMemsetAsync(deg, 0, (size_t)N_NODES * 4, stream);
    histrank_kernel<<<NB_EQ4, 256, 0, stream>>>(edge_idx, deg, rank4);
    scanA_kernel<<<NB_SCAN, 256, 0, stream>>>(deg, bsum);
    scanB_kernel<<<1, 512, 0, stream>>>(bsum, boff, row_start);
    scanC_kernel<<<NB_SCAN, 256, 0, stream>>>(deg, boff, row_start, col);
    scatter_kernel<<<NB_EQ4, 256, 0, stream>>>(edge_idx, rank4, row_start, col);

    gemm1_kernel<<<N_NODES / 32, 128, 0, stream>>>(node_feat, fw1, prm, flag,
                                                   h_bf, as_, ad_);
    agg1_kernel<<<N_NODES / 4, 256, 0, stream>>>(h_bf, as_, ad_, row_start, col,
                                                 prm + P_B1, prm + P_BNG, prm + P_BNB,
                                                 prm + P_BNM, prm + P_BNV, x1_bf);
    gemm2_kernel<<<N_NODES / 32, 128, 0, stream>>>(x1_bf, fw2, prm,
                                                   h_bf, as_, ad_);
    agg2_kernel<<<N_NODES / 4, 256, 0, stream>>>(h_bf, as_, ad_, row_start, col,
                                                 prm, x1_bf, flag, d_out);
}

// Round 10
// 371.266 us; speedup vs baseline: 1.0247x; 1.0247x over previous
//
#include <hip/hip_runtime.h>
#include <hip/hip_bf16.h>

#define N_NODES 100000
#define E_EDGES 1600000
#define ETOT    1700000   // E + N self-loops
#define NB_SCAN 391       // ceil(N/256)
#define EQ4     400000    // E_EDGES / 4
#define NB_EQ4  1563      // ceil(EQ4 / 256)
#define NGB     1563      // gemm1 sub-grid: ceil(N / 64)
#define F_IN    128
#define HC      64
#define OUT_C   40
#define NEG_SLOPE 0.2f
#define BN_EPS  1e-5f

// fp32 param block layout (element offsets)
#define P_W1   0
#define P_AS1  8192
#define P_AD1  8256
#define P_B1   8320
#define P_BNG  8384
#define P_BNB  8448
#define P_BNM  8512
#define P_BNV  8576
#define P_W2   8640
#define P_AS2  12736
#define P_AD2  12800
#define P_B2   12864
#define P_WF   12928
#define P_BF   15488
#define P_TOT  15528

typedef __attribute__((ext_vector_type(8))) short short8;
typedef __attribute__((ext_vector_type(4))) float floatx4;
typedef __attribute__((ext_vector_type(4))) unsigned int uintx4;

__device__ __forceinline__ unsigned short f2bf(float f) {   // RNE fp32->bf16
    unsigned int u = __float_as_uint(f);
    unsigned int r = u + 0x7FFFu + ((u >> 16) & 1u);
    return (unsigned short)(r >> 16);
}

__device__ __forceinline__ float leaky(float v) { return v > 0.f ? v : NEG_SLOPE * v; }

__device__ __forceinline__ float red64(float v) {
#pragma unroll
    for (int off = 32; off > 0; off >>= 1) v += __shfl_xor(v, off, 64);
    return v;
}
__device__ __forceinline__ float red16(float v) {
#pragma unroll
    for (int off = 8; off > 0; off >>= 1) v += __shfl_xor(v, off, 64);
    return v;
}

// ---------------- dtype detection ----------------
__global__ __launch_bounds__(64) void detect_kernel(const unsigned short* __restrict__ x,
                                                    int* __restrict__ flag) {
    int t = threadIdx.x;
    bool huge = false;
#pragma unroll
    for (int i = 0; i < 4; ++i) {
        unsigned short u = x[(t * 4 + i) * 2];
        float v = __uint_as_float(((unsigned int)u) << 16);
        if (!(fabsf(v) < 1e4f)) huge = true;
    }
    unsigned long long b = __ballot(huge);
    if (t == 0) *flag = (b != 0ull) ? 1 : 0;             // 1 => fp32 tensors
}

// ---------------- small-param conversion to fp32 ----------------
struct CvtArgs { const void* ptr[14]; int len[14]; };

__global__ __launch_bounds__(256) void cvt_params_kernel(CvtArgs a,
                                                         const int* __restrict__ flag,
                                                         float* __restrict__ dst) {
    int f = *flag;
    int i = blockIdx.x * 256 + threadIdx.x;
    if (i >= P_TOT) return;
    int k = 0, off = 0;
    while (i >= off + a.len[k]) { off += a.len[k]; ++k; }
    int j = i - off;
    float v = f ? ((const float*)a.ptr[k])[j]
                : __bfloat162float(((const __hip_bfloat16*)a.ptr[k])[j]);
    dst[i] = v;
}

// ---------------- W1/W2 -> bf16 MFMA B-fragment order ----------------
__global__ __launch_bounds__(256) void build_frags_kernel(const float* __restrict__ prm,
                                                          unsigned short* __restrict__ fw1,
                                                          unsigned short* __restrict__ fw2) {
    int i = blockIdx.x * 256 + threadIdx.x;
    if (i < 8192) {
        int j = i & 7, l = (i >> 3) & 63, q = (i >> 9) & 3, t = i >> 11;
        int k = q * 32 + (l >> 4) * 8 + j;
        int n = t * 16 + (l & 15);
        fw1[i] = f2bf(prm[P_W1 + k * 64 + n]);
    } else if (i < 12288) {
        int f = i - 8192;
        int j = f & 7, l = (f >> 3) & 63, q = (f >> 9) & 1, t = f >> 10;
        int k = q * 32 + (l >> 4) * 8 + j;
        int n = t * 16 + (l & 15);
        fw2[f] = f2bf(prm[P_W2 + k * 64 + n]);
    }
}

// ---------------- R15: FUSED histrank + gemm1 fat kernel ----------------
// histrank (edge stream + 1.6M rank atomics) and gemm1 (node_feat @ W1) are
// provably independent: hist writes deg/rank4, gemm1 writes h_bf/as_/ad_,
// and neither reads the other's output. Serial launches waste min(t_h,t_g);
// a fat kernel co-schedules the latency-bound atomic blocks with the MFMA
// blocks -> fused time ~ max instead of sum. Blocks [0,NB_EQ4) = hist role;
// [NB_EQ4, NB_EQ4+NGB) = gemm role (256 thr, 64 nodes/block, guarded tail).
__global__ __launch_bounds__(256) void fused_hist_gemm1_kernel(
        const int* __restrict__ ei, int* __restrict__ deg, int4* __restrict__ rank4,
        const void* __restrict__ x, const unsigned short* __restrict__ fw1,
        const float* __restrict__ prm, const int* __restrict__ flag,
        unsigned short* __restrict__ h_bf, float* __restrict__ as_,
        float* __restrict__ ad_) {
    __shared__ short lx[4 * 4 * 64 * 8];   // 16 KB (gemm role only)
    if (blockIdx.x < NB_EQ4) {
        // -------- histrank role: rank-based CSR pass (R12, confirmed win) --------
        int i4 = blockIdx.x * 256 + threadIdx.x;
        if (i4 >= EQ4) return;
        const unsigned long long* dst2 = (const unsigned long long*)(ei + E_EDGES);
        unsigned long long p0 = __builtin_nontemporal_load(&dst2[i4 * 2]);
        unsigned long long p1 = __builtin_nontemporal_load(&dst2[i4 * 2 + 1]);
        int d0 = (int)(p0 & 0xFFFFFFFFull), d1 = (int)(p0 >> 32);
        int d2 = (int)(p1 & 0xFFFFFFFFull), d3 = (int)(p1 >> 32);
        int4 r;
        r.x = atomicAdd(&deg[d0], 1);     // 4 independent atomics, all in flight
        r.y = atomicAdd(&deg[d1], 1);
        r.z = atomicAdd(&deg[d2], 1);
        r.w = atomicAdd(&deg[d3], 1);
        rank4[i4] = r;                    // coalesced 16B store
        return;
    }

    // -------- gemm1 role: h_bf[N,64] = x[N,128] @ W1, + fused alpha --------
    int t = threadIdx.x;
    int f = *flag;
    int base = (blockIdx.x - NB_EQ4) * 64;

#pragma unroll
    for (int i = 0; i < 4; ++i) {
        int cid = i * 256 + t;            // 0..1023 = 64 rows x 16 col-groups
        int m = cid >> 4, c = cid & 15;
        int q = c >> 2, g = c & 3;
        int loff = (((m >> 4) * 4 + q) * 64 + g * 16 + (m & 15)) * 8;
        int srow = base + m; if (srow > N_NODES - 1) srow = N_NODES - 1;  // tail clamp
        short8 s;
        if (f) {
            const float4* p = (const float4*)((const float*)x + ((size_t)srow << 7) + (c << 3));
            float4 u0 = p[0], u1 = p[1];
            s[0] = (short)f2bf(u0.x); s[1] = (short)f2bf(u0.y);
            s[2] = (short)f2bf(u0.z); s[3] = (short)f2bf(u0.w);
            s[4] = (short)f2bf(u1.x); s[5] = (short)f2bf(u1.y);
            s[6] = (short)f2bf(u1.z); s[7] = (short)f2bf(u1.w);
        } else {
            s = *(const short8*)((const unsigned short*)x + ((size_t)srow << 7) + (c << 3));
        }
        *(short8*)&lx[loff] = s;
    }
    __syncthreads();

    int w = t >> 6, lane = t & 63;
    short8 a[4];
#pragma unroll
    for (int q = 0; q < 4; ++q) a[q] = *(short8*)&lx[((w * 4 + q) * 64 + lane) * 8];

    const short8* bw = (const short8*)fw1;
    floatx4 acc[4];
#pragma unroll
    for (int tt = 0; tt < 4; ++tt) acc[tt] = (floatx4){0.f, 0.f, 0.f, 0.f};
#pragma unroll
    for (int tt = 0; tt < 4; ++tt) {
#pragma unroll
        for (int q = 0; q < 4; ++q) {
            short8 b = bw[(tt * 4 + q) * 64 + lane];
            acc[tt] = __builtin_amdgcn_mfma_f32_16x16x32_bf16(a[q], b, acc[tt], 0, 0, 0);
        }
    }

    int cl = lane & 15, grp = lane >> 4;
#pragma unroll
    for (int tt = 0; tt < 4; ++tt) {
#pragma unroll
        for (int r = 0; r < 4; ++r) {
            int node = base + w * 16 + grp * 4 + r;
            if (node < N_NODES)
                h_bf[(size_t)node * 64 + tt * 16 + cl] = f2bf(acc[tt][r]);
        }
    }

    float as0 = prm[P_AS1 + 0  + cl], as1 = prm[P_AS1 + 16 + cl],
          as2 = prm[P_AS1 + 32 + cl], as3 = prm[P_AS1 + 48 + cl];
    float ad0 = prm[P_AD1 + 0  + cl], ad1 = prm[P_AD1 + 16 + cl],
          ad2 = prm[P_AD1 + 32 + cl], ad3 = prm[P_AD1 + 48 + cl];
#pragma unroll
    for (int r = 0; r < 4; ++r) {
        float sh0 = red16(acc[0][r] * as0 + acc[1][r] * as1);
        float sh1 = red16(acc[2][r] * as2 + acc[3][r] * as3);
        float dh0 = red16(acc[0][r] * ad0 + acc[1][r] * ad1);
        float dh1 = red16(acc[2][r] * ad2 + acc[3][r] * ad3);
        int node = base + w * 16 + grp * 4 + r;
        if (cl == 0 && node < N_NODES) {
            as_[node * 2] = sh0;  as_[node * 2 + 1] = sh1;
            ad_[node * 2] = dh0;  ad_[node * 2 + 1] = dh1;
        }
    }
}

// parallel scan; degree counted as deg[i]+1 (self-loop folded in)
__global__ __launch_bounds__(256) void scanA_kernel(const int* __restrict__ deg,
                                                    int* __restrict__ bsum) {
    __shared__ int sm[256];
    int t = threadIdx.x;
    int i = blockIdx.x * 256 + t;
    sm[t] = (i < N_NODES) ? deg[i] + 1 : 0;
    __syncthreads();
    for (int off = 128; off > 0; off >>= 1) {
        if (t < off) sm[t] += sm[t + off];
        __syncthreads();
    }
    if (t == 0) bsum[blockIdx.x] = sm[0];
}

__global__ __launch_bounds__(512) void scanB_kernel(const int* __restrict__ bsum,
                                                    int* __restrict__ boff,
                                                    int* __restrict__ row_start) {
    __shared__ int sm[512];
    int t = threadIdx.x;
    int v = (t < NB_SCAN) ? bsum[t] : 0;
    sm[t] = v;
    __syncthreads();
    for (int off = 1; off < 512; off <<= 1) {
        int o = (t >= off) ? sm[t - off] : 0;
        __syncthreads();
        sm[t] += o;
        __syncthreads();
    }
    if (t < NB_SCAN) boff[t] = sm[t] - v;
    if (t == NB_SCAN - 1) row_start[N_NODES] = sm[t];   // == ETOT
}

__global__ __launch_bounds__(256) void scanC_kernel(const int* __restrict__ deg,
                                                    const int* __restrict__ boff,
                                                    int* __restrict__ row_start,
                                                    int* __restrict__ col) {
    __shared__ int sm[256];
    int t = threadIdx.x;
    int i = blockIdx.x * 256 + t;
    int v = (i < N_NODES) ? deg[i] + 1 : 0;
    sm[t] = v;
    __syncthreads();
    for (int off = 1; off < 256; off <<= 1) {
        int o = (t >= off) ? sm[t - off] : 0;
        __syncthreads();
        sm[t] += o;
        __syncthreads();
    }
    if (i < N_NODES) {
        int excl = sm[t] - v + boff[blockIdx.x];
        row_start[i] = excl;
        col[excl]    = i;              // slot 0 = self-loop
    }
}

// ---------------- atomic-free scatter: pure stream + independent stores ----------------
__global__ __launch_bounds__(256) void scatter_kernel(const int* __restrict__ ei,
                                                      const int4* __restrict__ rank4,
                                                      const int* __restrict__ row_start,
                                                      int* __restrict__ col) {
    int i4 = blockIdx.x * 256 + threadIdx.x;
    if (i4 >= EQ4) return;
    const unsigned long long* dst2 = (const unsigned long long*)(ei + E_EDGES);
    const unsigned long long* src2 = (const unsigned long long*)ei;
    unsigned long long p0 = __builtin_nontemporal_load(&dst2[i4 * 2]);
    unsigned long long p1 = __builtin_nontemporal_load(&dst2[i4 * 2 + 1]);
    unsigned long long q0 = __builtin_nontemporal_load(&src2[i4 * 2]);
    unsigned long long q1 = __builtin_nontemporal_load(&src2[i4 * 2 + 1]);
    int4 r = rank4[i4];
    int d0 = (int)(p0 & 0xFFFFFFFFull), d1 = (int)(p0 >> 32);
    int d2 = (int)(p1 & 0xFFFFFFFFull), d3 = (int)(p1 >> 32);
    int s0 = (int)(q0 & 0xFFFFFFFFull), s1 = (int)(q0 >> 32);
    int s2 = (int)(q1 & 0xFFFFFFFFull), s3 = (int)(q1 >> 32);
    int b0 = row_start[d0];            // 4 independent gathers (L2-resident)
    int b1 = row_start[d1];
    int b2 = row_start[d2];
    int b3 = row_start[d3];
    col[b0 + 1 + r.x] = s0;            // 4 independent stores, no round-trip
    col[b1 + 1 + r.y] = s1;
    col[b2 + 1 + r.z] = s2;
    col[b3 + 1 + r.w] = s3;
}

// ---------------- MFMA GEMM 2: h_bf = x1_bf[N,64] @ W2, + fused alpha ----------------
__global__ __launch_bounds__(128) void gemm2_kernel(const unsigned short* __restrict__ x1_bf,
                                                    const unsigned short* __restrict__ fw2,
                                                    const float* __restrict__ prm,
                                                    unsigned short* __restrict__ h_bf,
                                                    float* __restrict__ as_,
                                                    float* __restrict__ ad_) {
    __shared__ short lx[2 * 2 * 64 * 8];   // 4 KB
    int t = threadIdx.x;
    int base = blockIdx.x * 32;

#pragma unroll
    for (int i = 0; i < 2; ++i) {
        int cid = i * 128 + t;
        int m = cid >> 3, c = cid & 7;
        int q = c >> 2, g = c & 3;
        int loff = (((m >> 4) * 2 + q) * 64 + g * 16 + (m & 15)) * 8;
        short8 s = *(const short8*)(x1_bf + ((size_t)(base + m) << 6) + (c << 3));
        *(short8*)&lx[loff] = s;
    }
    __syncthreads();

    int w = t >> 6, lane = t & 63;
    short8 a[2];
#pragma unroll
    for (int q = 0; q < 2; ++q) a[q] = *(short8*)&lx[((w * 2 + q) * 64 + lane) * 8];

    const short8* bw = (const short8*)fw2;
    floatx4 acc[4];
#pragma unroll
    for (int tt = 0; tt < 4; ++tt) acc[tt] = (floatx4){0.f, 0.f, 0.f, 0.f};
#pragma unroll
    for (int tt = 0; tt < 4; ++tt) {
#pragma unroll
        for (int q = 0; q < 2; ++q) {
            short8 b = bw[(tt * 2 + q) * 64 + lane];
            acc[tt] = __builtin_amdgcn_mfma_f32_16x16x32_bf16(a[q], b, acc[tt], 0, 0, 0);
        }
    }

    int cl = lane & 15, grp = lane >> 4;
#pragma unroll
    for (int tt = 0; tt < 4; ++tt) {
#pragma unroll
        for (int r = 0; r < 4; ++r) {
            int node = base + w * 16 + grp * 4 + r;
            h_bf[(size_t)node * 64 + tt * 16 + cl] = f2bf(acc[tt][r]);
        }
    }

    float as0 = prm[P_AS2 + 0  + cl], as1 = prm[P_AS2 + 16 + cl],
          as2 = prm[P_AS2 + 32 + cl], as3 = prm[P_AS2 + 48 + cl];
    float ad0 = prm[P_AD2 + 0  + cl], ad1 = prm[P_AD2 + 16 + cl],
          ad2 = prm[P_AD2 + 32 + cl], ad3 = prm[P_AD2 + 48 + cl];
#pragma unroll
    for (int r = 0; r < 4; ++r) {
        float sh0 = red16(acc[0][r] * as0 + acc[1][r] * as1);
        float sh1 = red16(acc[2][r] * as2 + acc[3][r] * as3);
        float dh0 = red16(acc[0][r] * ad0 + acc[1][r] * ad1);
        float dh1 = red16(acc[2][r] * ad2 + acc[3][r] * ad3);
        if (cl == 0) {
            int node = base + w * 16 + grp * 4 + r;
            as_[node * 2] = sh0;  as_[node * 2 + 1] = sh1;
            ad_[node * 2] = dh0;  ad_[node * 2 + 1] = dh1;
        }
    }
}

// halving slot-reduction: lane ends with channel k=(lane&7) summed over its
// octet's 8 slots. 7 shfl + 14 sel + 7 add (vs 24/24/7 full butterfly).
// All shuffles convergent.
__device__ __forceinline__ float slot_reduce(float acc[8], int lane) {
    int slot = lane & 7;
    bool b2 = (slot & 4) != 0;
#pragma unroll
    for (int q = 0; q < 4; ++q) {
        float send = b2 ? acc[q] : acc[q + 4];
        float recv = __shfl_xor(send, 4, 64);
        acc[q] = (b2 ? acc[q + 4] : acc[q]) + recv;
    }
    bool b1 = (slot & 2) != 0;
#pragma unroll
    for (int q = 0; q < 2; ++q) {
        float send = b1 ? acc[q] : acc[q + 2];
        float recv = __shfl_xor(send, 2, 64);
        acc[q] = (b1 ? acc[q + 2] : acc[q]) + recv;
    }
    bool b0 = (slot & 1) != 0;
    float send = b0 ? acc[0] : acc[1];
    float recv = __shfl_xor(send, 1, 64);
    return (b0 ? acc[1] : acc[0]) + recv;
}

// ---------------- aggregation round batch (R14 pin kept, harmless) ----------------
template<int NK>
__device__ __forceinline__ void agg_rounds(const unsigned short* __restrict__ hb,
                                           const float* __restrict__ as_,
                                           const int* __restrict__ col,
                                           int rs, int koff, int last,
                                           int slot, int hi, float advh,
                                           float acc[8], float& sw) {
    int ce[NK]; float av[NK]; uintx4 dv[NK];
#pragma unroll
    for (int k = 0; k < NK; ++k) {
        int e = rs + koff + k * 8 + slot;
        ce[k] = col[e < last ? e : last];     // clamped: always valid
    }
#pragma unroll
    for (int k = 0; k < NK; ++k)
        dv[k] = *(const uintx4*)(hb + ((size_t)ce[k] << 6));
#pragma unroll
    for (int k = 0; k < NK; ++k)
        av[k] = as_[ce[k] * 2 + hi];

    if constexpr (NK == 1) {
        asm volatile("" : "+v"(dv[0]), "+v"(av[0]));
    } else if constexpr (NK == 2) {
        asm volatile("" : "+v"(dv[0]), "+v"(dv[1]), "+v"(av[0]), "+v"(av[1]));
    } else if constexpr (NK == 3) {
        asm volatile("" : "+v"(dv[0]), "+v"(dv[1]), "+v"(dv[2]),
                          "+v"(av[0]), "+v"(av[1]), "+v"(av[2]));
    } else {
        asm volatile("" : "+v"(dv[0]), "+v"(dv[1]), "+v"(dv[2]), "+v"(dv[3]),
                          "+v"(av[0]), "+v"(av[1]), "+v"(av[2]), "+v"(av[3]));
    }

#pragma unroll
    for (int k = 0; k < NK; ++k) {
        int e = rs + koff + k * 8 + slot;
        float w = (e <= last) ? __expf(leaky(av[k] + advh)) : 0.f;
        sw += w;
#pragma unroll
        for (int q = 0; q < 4; ++q) {
            unsigned int dw = dv[k][q];
            acc[2 * q]     = fmaf(w, __uint_as_float(dw << 16),         acc[2 * q]);
            acc[2 * q + 1] = fmaf(w, __uint_as_float(dw & 0xFFFF0000u), acc[2 * q + 1]);
        }
    }
}

// ---------------- aggregation core, slot-parallel, degree-adaptive ----------------
// R8 conclusion: agg is bound by the structural L2-fill floor (8 XCDs x
// 12.8 MB h_bf ~= the constant 105 MB FETCH) at ~1.75 TB/s random-fill rate.
// Shuffle-free loads (R10) + degree tiers (R13) + MLP pin (R14) kept.
__device__ __forceinline__ float agg_core(const unsigned short* __restrict__ h_bf,
                                          const float* __restrict__ as_,
                                          const float* __restrict__ ad_,
                                          const int* __restrict__ col,
                                          int v, int rs, int re, int lane) {
    int deg  = re - rs;
    int slot = lane & 7;
    int cg   = lane >> 3;        // channel group: my 8 channels = cg*8..cg*8+7
    int hi   = cg >> 2;          // head owning my channels
    if (deg <= 64) {
        float advh = ad_[v * 2 + hi];
        const unsigned short* hb = h_bf + (cg << 3);
        int last = re - 1;       // >= rs always (self-loop)
        float acc[8] = {0.f,0.f,0.f,0.f,0.f,0.f,0.f,0.f};
        float sw = 0.f;

        if (deg <= 8) {
            agg_rounds<1>(hb, as_, col, rs, 0, last, slot, hi, advh, acc, sw);
        } else if (deg <= 16) {
            agg_rounds<2>(hb, as_, col, rs, 0, last, slot, hi, advh, acc, sw);
        } else if (deg <= 24) {
            agg_rounds<3>(hb, as_, col, rs, 0, last, slot, hi, advh, acc, sw);
        } else {
            agg_rounds<4>(hb, as_, col, rs, 0, last, slot, hi, advh, acc, sw);
            if (deg > 32)
                agg_rounds<4>(hb, as_, col, rs, 32, last, slot, hi, advh, acc, sw);
        }

        // denominator: sum over the octet's 8 slots (3 convergent shuffles)
        sw += __shfl_xor(sw, 1, 64);
        sw += __shfl_xor(sw, 2, 64);
        sw += __shfl_xor(sw, 4, 64);
        float rdh = 1.f / (sw + 1e-16f);

        return slot_reduce(acc, lane) * rdh;
    } else {
        int head = lane >> 5;
        float adv0 = ad_[v * 2], adv1 = ad_[v * 2 + 1];
        float advh = head ? adv1 : adv0;
        float s0 = 0.f, s1 = 0.f;
        for (int e = rs + lane; e < re; e += 64) {
            int s = col[e];
            float2 av = *(const float2*)&as_[s * 2];
            s0 += __expf(leaky(av.x + adv0));
            s1 += __expf(leaky(av.y + adv1));
        }
        s0 = red64(s0); s1 = red64(s1);
        float rdh = 1.f / ((head ? s1 : s0) + 1e-16f);
        float a0 = 0.f;
        for (int e = rs; e < re; ++e) {
            int s = col[e];
            float w = __expf(leaky(as_[s * 2 + head] + advh));
            unsigned short u = h_bf[(size_t)s * 64 + lane];
            a0 = fmaf(w, __uint_as_float(((unsigned int)u) << 16), a0);
        }
        return a0 * rdh;
    }
}

// ---------------- aggregation layer 1 (+bias, BN eval, ELU) -> x1_bf ----------------
__global__ __launch_bounds__(256, 6) void agg1_kernel(const unsigned short* __restrict__ h_bf,
                                                   const float* __restrict__ as_,
                                                   const float* __restrict__ ad_,
                                                   const int* __restrict__ row_start,
                                                   const int* __restrict__ col,
                                                   const float* __restrict__ bias,
                                                   const float* __restrict__ bn_g,
                                                   const float* __restrict__ bn_b,
                                                   const float* __restrict__ bn_m,
                                                   const float* __restrict__ bn_v,
                                                   unsigned short* __restrict__ x1_bf) {
    int t = threadIdx.x, wid = t >> 6, lane = t & 63;
    int v = blockIdx.x * 4 + wid;
    int rs = row_start[v], re = row_start[v + 1];
    float acc = agg_core(h_bf, as_, ad_, col, v, rs, re, lane);
    float r = acc + bias[lane];
    float scale = bn_g[lane] * rsqrtf(bn_v[lane] + BN_EPS);
    r = (r - bn_m[lane]) * scale + bn_b[lane];
    r = r > 0.f ? r : expm1f(r);   // ELU
    x1_bf[(size_t)v * 64 + lane] = f2bf(r);
}

// ---------------- agg layer 2 + JK max + fused projection -> out [N,40] ----------------
__global__ __launch_bounds__(256, 6) void agg2_kernel(const unsigned short* __restrict__ h_bf,
                                                   const float* __restrict__ as_,
                                                   const float* __restrict__ ad_,
                                                   const int* __restrict__ row_start,
                                                   const int* __restrict__ col,
                                                   const float* __restrict__ prm,
                                                   const unsigned short* __restrict__ x1_bf,
                                                   const int* __restrict__ flag,
                                                   void* __restrict__ out) {
    __shared__ float Wfs[2560];      // Wf[c*40+o] natural layout: lanes o stride-1 -> conflict-free
    __shared__ float xsh[4][64];
    int t = threadIdx.x;
#pragma unroll
    for (int i = 0; i < 10; ++i) Wfs[i * 256 + t] = prm[P_WF + i * 256 + t];

    int wid = t >> 6, lane = t & 63;
    int v = blockIdx.x * 4 + wid;
    int rs = row_start[v], re = row_start[v + 1];
    float acc = agg_core(h_bf, as_, ad_, col, v, rs, re, lane);
    float x2 = acc + prm[P_B2 + lane];
    unsigned short u = x1_bf[(size_t)v * 64 + lane];
    float x1v = __uint_as_float(((unsigned int)u) << 16);
    xsh[wid][lane] = fmaxf(x1v, x2);   // JumpingKnowledge max
    __syncthreads();

    if (t < 160) {                     // 4 nodes x 40 outputs
        int n = t / 40, o = t - n * 40;
        float po = 0.f;
#pragma unroll
        for (int c = 0; c < 64; c += 4) {
            po = fmaf(xsh[n][c],     Wfs[c * 40 + o],       po);
            po = fmaf(xsh[n][c + 1], Wfs[(c + 1) * 40 + o], po);
            po = fmaf(xsh[n][c + 2], Wfs[(c + 2) * 40 + o], po);
            po = fmaf(xsh[n][c + 3], Wfs[(c + 3) * 40 + o], po);
        }
        float r = po + prm[P_BF + o];
        size_t idx = (size_t)(blockIdx.x * 4 + n) * 40 + o;
        if (*flag) ((float*)out)[idx] = r;
        else ((__hip_bfloat16*)out)[idx] = __float2bfloat16(r);
    }
}

extern "C" void kernel_launch(void* const* d_in, const int* in_sizes, int n_in,
                              void* d_out, int out_size, void* d_ws, size_t ws_size,
                              hipStream_t stream) {
    (void)in_sizes; (void)n_in; (void)out_size; (void)ws_size;
    const void* node_feat = d_in[0];
    const int*  edge_idx  = (const int*)d_in[1];

    char* ws = (char*)d_ws;
    size_t off = 0;
    auto alloc = [&](size_t bytes) -> void* {
        void* p = ws + off;
        off += (bytes + 255) & ~(size_t)255;
        return p;
    };
    unsigned short* h_bf  = (unsigned short*)alloc((size_t)N_NODES * 64 * 2);  // 12.8 MB
    unsigned short* x1_bf = (unsigned short*)alloc((size_t)N_NODES * 64 * 2);  // 12.8 MB
    float* as_ = (float*)alloc((size_t)N_NODES * 2 * 4);
    float* ad_ = (float*)alloc((size_t)N_NODES * 2 * 4);
    int* deg       = (int*)alloc((size_t)N_NODES * 4);
    int* row_start = (int*)alloc((size_t)(N_NODES + 1) * 4);
    int4* rank4    = (int4*)alloc((size_t)EQ4 * 16);        // 6.4 MB (32-bit ranks)
    int* col       = (int*)alloc((size_t)ETOT * 4);         // 6.8 MB
    int* bsum      = (int*)alloc((size_t)NB_SCAN * 4);
    int* boff      = (int*)alloc((size_t)NB_SCAN * 4);
    float* prm     = (float*)alloc((size_t)P_TOT * 4);
    unsigned short* fw1 = (unsigned short*)alloc(8192 * 2);
    unsigned short* fw2 = (unsigned short*)alloc(4096 * 2);
    int* flag      = (int*)alloc(256);

    detect_kernel<<<1, 64, 0, stream>>>((const unsigned short*)node_feat, flag);
    CvtArgs ca;
    const int lens[14] = {8192, 64, 64, 64, 64, 64, 64, 64, 4096, 64, 64, 64, 2560, 40};
    for (int i = 0; i < 14; ++i) { ca.ptr[i] = d_in[i + 2]; ca.len[i] = lens[i]; }
    cvt_params_kernel<<<(P_TOT + 255) / 256, 256, 0, stream>>>(ca, flag, prm);
    build_frags_kernel<<<48, 256, 0, stream>>>(prm, fw1, fw2);

    // R15: histrank and gemm1 are independent -> one fat kernel (hist blocks
    // first, gemm blocks follow); fused time ~ max instead of sum.
    hipMemsetAsync(deg, 0, (size_t)N_NODES * 4, stream);
    fused_hist_gemm1_kernel<<<NB_EQ4 + NGB, 256, 0, stream>>>(
        edge_idx, deg, rank4, node_feat, fw1, prm, flag, h_bf, as_, ad_);
    scanA_kernel<<<NB_SCAN, 256, 0, stream>>>(deg, bsum);
    scanB_kernel<<<1, 512, 0, stream>>>(bsum, boff, row_start);
    scanC_kernel<<<NB_SCAN, 256, 0, stream>>>(deg, boff, row_start, col);
    scatter_kernel<<<NB_EQ4, 256, 0, stream>>>(edge_idx, rank4, row_start, col);

    agg1_kernel<<<N_NODES / 4, 256, 0, stream>>>(h_bf, as_, ad_, row_start, col,
                                                 prm + P_B1, prm + P_BNG, prm + P_BNB,
                                                 prm + P_BNM, prm + P_BNV, x1_bf);
    gemm2_kernel<<<N_NODES / 32, 128, 0, stream>>>(x1_bf, fw2, prm,
                                                   h_bf, as_, ad_);
    agg2_kernel<<<N_NODES / 4, 256, 0, stream>>>(h_bf, as_, ad_, row_start, col,
                                                 prm, x1_bf, flag, d_out);
}

// Round 11
// 367.016 us; speedup vs baseline: 1.0366x; 1.0116x over previous
//
#include <hip/hip_runtime.h>
#include <hip/hip_bf16.h>

#define N_NODES 100000
#define E_EDGES 1600000
#define ETOT    1700000   // E + N self-loops
#define NB_SCAN 391       // ceil(N/256)
#define EQ4     400000    // E_EDGES / 4
#define NB_EQ4  1563      // ceil(EQ4 / 256)
#define EQ8     200000    // E_EDGES / 8
#define NB_EQ8  782       // ceil(EQ8 / 256)
#define NGB     1563      // gemm1 sub-grid: ceil(N / 64)
#define F_IN    128
#define HC      64
#define OUT_C   40
#define NEG_SLOPE 0.2f
#define BN_EPS  1e-5f

// fp32 param block layout (element offsets)
#define P_W1   0
#define P_AS1  8192
#define P_AD1  8256
#define P_B1   8320
#define P_BNG  8384
#define P_BNB  8448
#define P_BNM  8512
#define P_BNV  8576
#define P_W2   8640
#define P_AS2  12736
#define P_AD2  12800
#define P_B2   12864
#define P_WF   12928
#define P_BF   15488
#define P_TOT  15528

typedef __attribute__((ext_vector_type(8))) short short8;
typedef __attribute__((ext_vector_type(4))) float floatx4;
typedef __attribute__((ext_vector_type(4))) unsigned int uintx4;

__device__ __forceinline__ unsigned short f2bf(float f) {   // RNE fp32->bf16
    unsigned int u = __float_as_uint(f);
    unsigned int r = u + 0x7FFFu + ((u >> 16) & 1u);
    return (unsigned short)(r >> 16);
}

__device__ __forceinline__ float leaky(float v) { return v > 0.f ? v : NEG_SLOPE * v; }

__device__ __forceinline__ float red64(float v) {
#pragma unroll
    for (int off = 32; off > 0; off >>= 1) v += __shfl_xor(v, off, 64);
    return v;
}
__device__ __forceinline__ float red16(float v) {
#pragma unroll
    for (int off = 8; off > 0; off >>= 1) v += __shfl_xor(v, off, 64);
    return v;
}

// ---------------- dtype detection ----------------
__global__ __launch_bounds__(64) void detect_kernel(const unsigned short* __restrict__ x,
                                                    int* __restrict__ flag) {
    int t = threadIdx.x;
    bool huge = false;
#pragma unroll
    for (int i = 0; i < 4; ++i) {
        unsigned short u = x[(t * 4 + i) * 2];
        float v = __uint_as_float(((unsigned int)u) << 16);
        if (!(fabsf(v) < 1e4f)) huge = true;
    }
    unsigned long long b = __ballot(huge);
    if (t == 0) *flag = (b != 0ull) ? 1 : 0;             // 1 => fp32 tensors
}

// ---------------- small-param conversion to fp32 ----------------
struct CvtArgs { const void* ptr[14]; int len[14]; };

__global__ __launch_bounds__(256) void cvt_params_kernel(CvtArgs a,
                                                         const int* __restrict__ flag,
                                                         float* __restrict__ dst) {
    int f = *flag;
    int i = blockIdx.x * 256 + threadIdx.x;
    if (i >= P_TOT) return;
    int k = 0, off = 0;
    while (i >= off + a.len[k]) { off += a.len[k]; ++k; }
    int j = i - off;
    float v = f ? ((const float*)a.ptr[k])[j]
                : __bfloat162float(((const __hip_bfloat16*)a.ptr[k])[j]);
    dst[i] = v;
}

// ---------------- W1/W2 -> bf16 MFMA B-fragment order ----------------
__global__ __launch_bounds__(256) void build_frags_kernel(const float* __restrict__ prm,
                                                          unsigned short* __restrict__ fw1,
                                                          unsigned short* __restrict__ fw2) {
    int i = blockIdx.x * 256 + threadIdx.x;
    if (i < 8192) {
        int j = i & 7, l = (i >> 3) & 63, q = (i >> 9) & 3, t = i >> 11;
        int k = q * 32 + (l >> 4) * 8 + j;
        int n = t * 16 + (l & 15);
        fw1[i] = f2bf(prm[P_W1 + k * 64 + n]);
    } else if (i < 12288) {
        int f = i - 8192;
        int j = f & 7, l = (f >> 3) & 63, q = (f >> 9) & 1, t = f >> 10;
        int k = q * 32 + (l >> 4) * 8 + j;
        int n = t * 16 + (l & 15);
        fw2[f] = f2bf(prm[P_W2 + k * 64 + n]);
    }
}

// ---------------- R15/R16: FUSED histrank + gemm1 fat kernel ----------------
// R10 PMC on fused: VALUBusy 4.7%, MfmaUtil 0.7%, WRITE 70MB (~50MB = atomic
// round-trips) -> the 84us is the hist role's RETURNING atomics, latency-
// bound with only 4 in flight per thread. R16: 8 edges/thread -> 8
// independent atomics in flight, halving exposed latency per atomic.
// rank4 quad layout unchanged (thread i8 writes quads 2*i8, 2*i8+1).
__global__ __launch_bounds__(256) void fused_hist_gemm1_kernel(
        const int* __restrict__ ei, int* __restrict__ deg, int4* __restrict__ rank4,
        const void* __restrict__ x, const unsigned short* __restrict__ fw1,
        const float* __restrict__ prm, const int* __restrict__ flag,
        unsigned short* __restrict__ h_bf, float* __restrict__ as_,
        float* __restrict__ ad_) {
    __shared__ short lx[4 * 4 * 64 * 8];   // 16 KB (gemm role only)
    if (blockIdx.x < NB_EQ8) {
        // -------- histrank role: 8 edges/thread, 8 atomics in flight --------
        int i8 = blockIdx.x * 256 + threadIdx.x;
        if (i8 >= EQ8) return;
        const unsigned long long* dst2 = (const unsigned long long*)(ei + E_EDGES);
        unsigned long long p0 = __builtin_nontemporal_load(&dst2[i8 * 4]);
        unsigned long long p1 = __builtin_nontemporal_load(&dst2[i8 * 4 + 1]);
        unsigned long long p2 = __builtin_nontemporal_load(&dst2[i8 * 4 + 2]);
        unsigned long long p3 = __builtin_nontemporal_load(&dst2[i8 * 4 + 3]);
        int d0 = (int)(p0 & 0xFFFFFFFFull), d1 = (int)(p0 >> 32);
        int d2 = (int)(p1 & 0xFFFFFFFFull), d3 = (int)(p1 >> 32);
        int d4 = (int)(p2 & 0xFFFFFFFFull), d5 = (int)(p2 >> 32);
        int d6 = (int)(p3 & 0xFFFFFFFFull), d7 = (int)(p3 >> 32);
        int r0 = atomicAdd(&deg[d0], 1);   // 8 independent atomics, all in flight
        int r1 = atomicAdd(&deg[d1], 1);
        int r2 = atomicAdd(&deg[d2], 1);
        int r3 = atomicAdd(&deg[d3], 1);
        int r4 = atomicAdd(&deg[d4], 1);
        int r5 = atomicAdd(&deg[d5], 1);
        int r6 = atomicAdd(&deg[d6], 1);
        int r7 = atomicAdd(&deg[d7], 1);
        rank4[i8 * 2]     = make_int4(r0, r1, r2, r3);   // coalesced 16B stores
        rank4[i8 * 2 + 1] = make_int4(r4, r5, r6, r7);
        return;
    }

    // -------- gemm1 role: h_bf[N,64] = x[N,128] @ W1, + fused alpha --------
    int t = threadIdx.x;
    int f = *flag;
    int base = (blockIdx.x - NB_EQ8) * 64;

#pragma unroll
    for (int i = 0; i < 4; ++i) {
        int cid = i * 256 + t;            // 0..1023 = 64 rows x 16 col-groups
        int m = cid >> 4, c = cid & 15;
        int q = c >> 2, g = c & 3;
        int loff = (((m >> 4) * 4 + q) * 64 + g * 16 + (m & 15)) * 8;
        int srow = base + m; if (srow > N_NODES - 1) srow = N_NODES - 1;  // tail clamp
        short8 s;
        if (f) {
            const float4* p = (const float4*)((const float*)x + ((size_t)srow << 7) + (c << 3));
            float4 u0 = p[0], u1 = p[1];
            s[0] = (short)f2bf(u0.x); s[1] = (short)f2bf(u0.y);
            s[2] = (short)f2bf(u0.z); s[3] = (short)f2bf(u0.w);
            s[4] = (short)f2bf(u1.x); s[5] = (short)f2bf(u1.y);
            s[6] = (short)f2bf(u1.z); s[7] = (short)f2bf(u1.w);
        } else {
            s = *(const short8*)((const unsigned short*)x + ((size_t)srow << 7) + (c << 3));
        }
        *(short8*)&lx[loff] = s;
    }
    __syncthreads();

    int w = t >> 6, lane = t & 63;
    short8 a[4];
#pragma unroll
    for (int q = 0; q < 4; ++q) a[q] = *(short8*)&lx[((w * 4 + q) * 64 + lane) * 8];

    const short8* bw = (const short8*)fw1;
    floatx4 acc[4];
#pragma unroll
    for (int tt = 0; tt < 4; ++tt) acc[tt] = (floatx4){0.f, 0.f, 0.f, 0.f};
#pragma unroll
    for (int tt = 0; tt < 4; ++tt) {
#pragma unroll
        for (int q = 0; q < 4; ++q) {
            short8 b = bw[(tt * 4 + q) * 64 + lane];
            acc[tt] = __builtin_amdgcn_mfma_f32_16x16x32_bf16(a[q], b, acc[tt], 0, 0, 0);
        }
    }

    int cl = lane & 15, grp = lane >> 4;
#pragma unroll
    for (int tt = 0; tt < 4; ++tt) {
#pragma unroll
        for (int r = 0; r < 4; ++r) {
            int node = base + w * 16 + grp * 4 + r;
            if (node < N_NODES)
                h_bf[(size_t)node * 64 + tt * 16 + cl] = f2bf(acc[tt][r]);
        }
    }

    float as0 = prm[P_AS1 + 0  + cl], as1 = prm[P_AS1 + 16 + cl],
          as2 = prm[P_AS1 + 32 + cl], as3 = prm[P_AS1 + 48 + cl];
    float ad0 = prm[P_AD1 + 0  + cl], ad1 = prm[P_AD1 + 16 + cl],
          ad2 = prm[P_AD1 + 32 + cl], ad3 = prm[P_AD1 + 48 + cl];
#pragma unroll
    for (int r = 0; r < 4; ++r) {
        float sh0 = red16(acc[0][r] * as0 + acc[1][r] * as1);
        float sh1 = red16(acc[2][r] * as2 + acc[3][r] * as3);
        float dh0 = red16(acc[0][r] * ad0 + acc[1][r] * ad1);
        float dh1 = red16(acc[2][r] * ad2 + acc[3][r] * ad3);
        int node = base + w * 16 + grp * 4 + r;
        if (cl == 0 && node < N_NODES) {
            as_[node * 2] = sh0;  as_[node * 2 + 1] = sh1;
            ad_[node * 2] = dh0;  ad_[node * 2 + 1] = dh1;
        }
    }
}

// parallel scan; degree counted as deg[i]+1 (self-loop folded in)
__global__ __launch_bounds__(256) void scanA_kernel(const int* __restrict__ deg,
                                                    int* __restrict__ bsum) {
    __shared__ int sm[256];
    int t = threadIdx.x;
    int i = blockIdx.x * 256 + t;
    sm[t] = (i < N_NODES) ? deg[i] + 1 : 0;
    __syncthreads();
    for (int off = 128; off > 0; off >>= 1) {
        if (t < off) sm[t] += sm[t + off];
        __syncthreads();
    }
    if (t == 0) bsum[blockIdx.x] = sm[0];
}

__global__ __launch_bounds__(512) void scanB_kernel(const int* __restrict__ bsum,
                                                    int* __restrict__ boff,
                                                    int* __restrict__ row_start) {
    __shared__ int sm[512];
    int t = threadIdx.x;
    int v = (t < NB_SCAN) ? bsum[t] : 0;
    sm[t] = v;
    __syncthreads();
    for (int off = 1; off < 512; off <<= 1) {
        int o = (t >= off) ? sm[t - off] : 0;
        __syncthreads();
        sm[t] += o;
        __syncthreads();
    }
    if (t < NB_SCAN) boff[t] = sm[t] - v;
    if (t == NB_SCAN - 1) row_start[N_NODES] = sm[t];   // == ETOT
}

__global__ __launch_bounds__(256) void scanC_kernel(const int* __restrict__ deg,
                                                    const int* __restrict__ boff,
                                                    int* __restrict__ row_start,
                                                    int* __restrict__ col) {
    __shared__ int sm[256];
    int t = threadIdx.x;
    int i = blockIdx.x * 256 + t;
    int v = (i < N_NODES) ? deg[i] + 1 : 0;
    sm[t] = v;
    __syncthreads();
    for (int off = 1; off < 256; off <<= 1) {
        int o = (t >= off) ? sm[t - off] : 0;
        __syncthreads();
        sm[t] += o;
        __syncthreads();
    }
    if (i < N_NODES) {
        int excl = sm[t] - v + boff[blockIdx.x];
        row_start[i] = excl;
        col[excl]    = i;              // slot 0 = self-loop
    }
}

// ---------------- atomic-free scatter: pure stream + independent stores ----------------
__global__ __launch_bounds__(256) void scatter_kernel(const int* __restrict__ ei,
                                                      const int4* __restrict__ rank4,
                                                      const int* __restrict__ row_start,
                                                      int* __restrict__ col) {
    int i4 = blockIdx.x * 256 + threadIdx.x;
    if (i4 >= EQ4) return;
    const unsigned long long* dst2 = (const unsigned long long*)(ei + E_EDGES);
    const unsigned long long* src2 = (const unsigned long long*)ei;
    unsigned long long p0 = __builtin_nontemporal_load(&dst2[i4 * 2]);
    unsigned long long p1 = __builtin_nontemporal_load(&dst2[i4 * 2 + 1]);
    unsigned long long q0 = __builtin_nontemporal_load(&src2[i4 * 2]);
    unsigned long long q1 = __builtin_nontemporal_load(&src2[i4 * 2 + 1]);
    int4 r = rank4[i4];
    int d0 = (int)(p0 & 0xFFFFFFFFull), d1 = (int)(p0 >> 32);
    int d2 = (int)(p1 & 0xFFFFFFFFull), d3 = (int)(p1 >> 32);
    int s0 = (int)(q0 & 0xFFFFFFFFull), s1 = (int)(q0 >> 32);
    int s2 = (int)(q1 & 0xFFFFFFFFull), s3 = (int)(q1 >> 32);
    int b0 = row_start[d0];            // 4 independent gathers (L2-resident)
    int b1 = row_start[d1];
    int b2 = row_start[d2];
    int b3 = row_start[d3];
    col[b0 + 1 + r.x] = s0;            // 4 independent stores, no round-trip
    col[b1 + 1 + r.y] = s1;
    col[b2 + 1 + r.z] = s2;
    col[b3 + 1 + r.w] = s3;
}

// ---------------- MFMA GEMM 2: h_bf = x1_bf[N,64] @ W2, + fused alpha ----------------
__global__ __launch_bounds__(128) void gemm2_kernel(const unsigned short* __restrict__ x1_bf,
                                                    const unsigned short* __restrict__ fw2,
                                                    const float* __restrict__ prm,
                                                    unsigned short* __restrict__ h_bf,
                                                    float* __restrict__ as_,
                                                    float* __restrict__ ad_) {
    __shared__ short lx[2 * 2 * 64 * 8];   // 4 KB
    int t = threadIdx.x;
    int base = blockIdx.x * 32;

#pragma unroll
    for (int i = 0; i < 2; ++i) {
        int cid = i * 128 + t;
        int m = cid >> 3, c = cid & 7;
        int q = c >> 2, g = c & 3;
        int loff = (((m >> 4) * 2 + q) * 64 + g * 16 + (m & 15)) * 8;
        short8 s = *(const short8*)(x1_bf + ((size_t)(base + m) << 6) + (c << 3));
        *(short8*)&lx[loff] = s;
    }
    __syncthreads();

    int w = t >> 6, lane = t & 63;
    short8 a[2];
#pragma unroll
    for (int q = 0; q < 2; ++q) a[q] = *(short8*)&lx[((w * 2 + q) * 64 + lane) * 8];

    const short8* bw = (const short8*)fw2;
    floatx4 acc[4];
#pragma unroll
    for (int tt = 0; tt < 4; ++tt) acc[tt] = (floatx4){0.f, 0.f, 0.f, 0.f};
#pragma unroll
    for (int tt = 0; tt < 4; ++tt) {
#pragma unroll
        for (int q = 0; q < 2; ++q) {
            short8 b = bw[(tt * 2 + q) * 64 + lane];
            acc[tt] = __builtin_amdgcn_mfma_f32_16x16x32_bf16(a[q], b, acc[tt], 0, 0, 0);
        }
    }

    int cl = lane & 15, grp = lane >> 4;
#pragma unroll
    for (int tt = 0; tt < 4; ++tt) {
#pragma unroll
        for (int r = 0; r < 4; ++r) {
            int node = base + w * 16 + grp * 4 + r;
            h_bf[(size_t)node * 64 + tt * 16 + cl] = f2bf(acc[tt][r]);
        }
    }

    float as0 = prm[P_AS2 + 0  + cl], as1 = prm[P_AS2 + 16 + cl],
          as2 = prm[P_AS2 + 32 + cl], as3 = prm[P_AS2 + 48 + cl];
    float ad0 = prm[P_AD2 + 0  + cl], ad1 = prm[P_AD2 + 16 + cl],
          ad2 = prm[P_AD2 + 32 + cl], ad3 = prm[P_AD2 + 48 + cl];
#pragma unroll
    for (int r = 0; r < 4; ++r) {
        float sh0 = red16(acc[0][r] * as0 + acc[1][r] * as1);
        float sh1 = red16(acc[2][r] * as2 + acc[3][r] * as3);
        float dh0 = red16(acc[0][r] * ad0 + acc[1][r] * ad1);
        float dh1 = red16(acc[2][r] * ad2 + acc[3][r] * ad3);
        if (cl == 0) {
            int node = base + w * 16 + grp * 4 + r;
            as_[node * 2] = sh0;  as_[node * 2 + 1] = sh1;
            ad_[node * 2] = dh0;  ad_[node * 2 + 1] = dh1;
        }
    }
}

// halving slot-reduction: lane ends with channel k=(lane&7) summed over its
// octet's 8 slots. 7 shfl + 14 sel + 7 add (vs 24/24/7 full butterfly).
// All shuffles convergent.
__device__ __forceinline__ float slot_reduce(float acc[8], int lane) {
    int slot = lane & 7;
    bool b2 = (slot & 4) != 0;
#pragma unroll
    for (int q = 0; q < 4; ++q) {
        float send = b2 ? acc[q] : acc[q + 4];
        float recv = __shfl_xor(send, 4, 64);
        acc[q] = (b2 ? acc[q + 4] : acc[q]) + recv;
    }
    bool b1 = (slot & 2) != 0;
#pragma unroll
    for (int q = 0; q < 2; ++q) {
        float send = b1 ? acc[q] : acc[q + 2];
        float recv = __shfl_xor(send, 2, 64);
        acc[q] = (b1 ? acc[q + 2] : acc[q]) + recv;
    }
    bool b0 = (slot & 1) != 0;
    float send = b0 ? acc[0] : acc[1];
    float recv = __shfl_xor(send, 1, 64);
    return (b0 ? acc[1] : acc[0]) + recv;
}

// ---------------- aggregation round batch (R14 pin kept, harmless) ----------------
template<int NK>
__device__ __forceinline__ void agg_rounds(const unsigned short* __restrict__ hb,
                                           const float* __restrict__ as_,
                                           const int* __restrict__ col,
                                           int rs, int koff, int last,
                                           int slot, int hi, float advh,
                                           float acc[8], float& sw) {
    int ce[NK]; float av[NK]; uintx4 dv[NK];
#pragma unroll
    for (int k = 0; k < NK; ++k) {
        int e = rs + koff + k * 8 + slot;
        ce[k] = col[e < last ? e : last];     // clamped: always valid
    }
#pragma unroll
    for (int k = 0; k < NK; ++k)
        dv[k] = *(const uintx4*)(hb + ((size_t)ce[k] << 6));
#pragma unroll
    for (int k = 0; k < NK; ++k)
        av[k] = as_[ce[k] * 2 + hi];

    if constexpr (NK == 1) {
        asm volatile("" : "+v"(dv[0]), "+v"(av[0]));
    } else if constexpr (NK == 2) {
        asm volatile("" : "+v"(dv[0]), "+v"(dv[1]), "+v"(av[0]), "+v"(av[1]));
    } else if constexpr (NK == 3) {
        asm volatile("" : "+v"(dv[0]), "+v"(dv[1]), "+v"(dv[2]),
                          "+v"(av[0]), "+v"(av[1]), "+v"(av[2]));
    } else {
        asm volatile("" : "+v"(dv[0]), "+v"(dv[1]), "+v"(dv[2]), "+v"(dv[3]),
                          "+v"(av[0]), "+v"(av[1]), "+v"(av[2]), "+v"(av[3]));
    }

#pragma unroll
    for (int k = 0; k < NK; ++k) {
        int e = rs + koff + k * 8 + slot;
        float w = (e <= last) ? __expf(leaky(av[k] + advh)) : 0.f;
        sw += w;
#pragma unroll
        for (int q = 0; q < 4; ++q) {
            unsigned int dw = dv[k][q];
            acc[2 * q]     = fmaf(w, __uint_as_float(dw << 16),         acc[2 * q]);
            acc[2 * q + 1] = fmaf(w, __uint_as_float(dw & 0xFFFF0000u), acc[2 * q + 1]);
        }
    }
}

// ---------------- aggregation core, slot-parallel, degree-adaptive ----------------
// R8 conclusion: agg is bound by the structural L2-fill floor (8 XCDs x
// 12.8 MB h_bf ~= the constant 105 MB FETCH) at ~1.75 TB/s random-fill rate.
// Shuffle-free loads (R10) + degree tiers (R13) + MLP pin (R14) kept.
__device__ __forceinline__ float agg_core(const unsigned short* __restrict__ h_bf,
                                          const float* __restrict__ as_,
                                          const float* __restrict__ ad_,
                                          const int* __restrict__ col,
                                          int v, int rs, int re, int lane) {
    int deg  = re - rs;
    int slot = lane & 7;
    int cg   = lane >> 3;        // channel group: my 8 channels = cg*8..cg*8+7
    int hi   = cg >> 2;          // head owning my channels
    if (deg <= 64) {
        float advh = ad_[v * 2 + hi];
        const unsigned short* hb = h_bf + (cg << 3);
        int last = re - 1;       // >= rs always (self-loop)
        float acc[8] = {0.f,0.f,0.f,0.f,0.f,0.f,0.f,0.f};
        float sw = 0.f;

        if (deg <= 8) {
            agg_rounds<1>(hb, as_, col, rs, 0, last, slot, hi, advh, acc, sw);
        } else if (deg <= 16) {
            agg_rounds<2>(hb, as_, col, rs, 0, last, slot, hi, advh, acc, sw);
        } else if (deg <= 24) {
            agg_rounds<3>(hb, as_, col, rs, 0, last, slot, hi, advh, acc, sw);
        } else {
            agg_rounds<4>(hb, as_, col, rs, 0, last, slot, hi, advh, acc, sw);
            if (deg > 32)
                agg_rounds<4>(hb, as_, col, rs, 32, last, slot, hi, advh, acc, sw);
        }

        // denominator: sum over the octet's 8 slots (3 convergent shuffles)
        sw += __shfl_xor(sw, 1, 64);
        sw += __shfl_xor(sw, 2, 64);
        sw += __shfl_xor(sw, 4, 64);
        float rdh = 1.f / (sw + 1e-16f);

        return slot_reduce(acc, lane) * rdh;
    } else {
        int head = lane >> 5;
        float adv0 = ad_[v * 2], adv1 = ad_[v * 2 + 1];
        float advh = head ? adv1 : adv0;
        float s0 = 0.f, s1 = 0.f;
        for (int e = rs + lane; e < re; e += 64) {
            int s = col[e];
            float2 av = *(const float2*)&as_[s * 2];
            s0 += __expf(leaky(av.x + adv0));
            s1 += __expf(leaky(av.y + adv1));
        }
        s0 = red64(s0); s1 = red64(s1);
        float rdh = 1.f / ((head ? s1 : s0) + 1e-16f);
        float a0 = 0.f;
        for (int e = rs; e < re; ++e) {
            int s = col[e];
            float w = __expf(leaky(as_[s * 2 + head] + advh));
            unsigned short u = h_bf[(size_t)s * 64 + lane];
            a0 = fmaf(w, __uint_as_float(((unsigned int)u) << 16), a0);
        }
        return a0 * rdh;
    }
}

// ---------------- aggregation layer 1 (+bias, BN eval, ELU) -> x1_bf ----------------
__global__ __launch_bounds__(256, 6) void agg1_kernel(const unsigned short* __restrict__ h_bf,
                                                   const float* __restrict__ as_,
                                                   const float* __restrict__ ad_,
                                                   const int* __restrict__ row_start,
                                                   const int* __restrict__ col,
                                                   const float* __restrict__ bias,
                                                   const float* __restrict__ bn_g,
                                                   const float* __restrict__ bn_b,
                                                   const float* __restrict__ bn_m,
                                                   const float* __restrict__ bn_v,
                                                   unsigned short* __restrict__ x1_bf) {
    int t = threadIdx.x, wid = t >> 6, lane = t & 63;
    int v = blockIdx.x * 4 + wid;
    int rs = row_start[v], re = row_start[v + 1];
    float acc = agg_core(h_bf, as_, ad_, col, v, rs, re, lane);
    float r = acc + bias[lane];
    float scale = bn_g[lane] * rsqrtf(bn_v[lane] + BN_EPS);
    r = (r - bn_m[lane]) * scale + bn_b[lane];
    r = r > 0.f ? r : expm1f(r);   // ELU
    x1_bf[(size_t)v * 64 + lane] = f2bf(r);
}

// ---------------- agg layer 2 + JK max + fused projection -> out [N,40] ----------------
__global__ __launch_bounds__(256, 6) void agg2_kernel(const unsigned short* __restrict__ h_bf,
                                                   const float* __restrict__ as_,
                                                   const float* __restrict__ ad_,
                                                   const int* __restrict__ row_start,
                                                   const int* __restrict__ col,
                                                   const float* __restrict__ prm,
                                                   const unsigned short* __restrict__ x1_bf,
                                                   const int* __restrict__ flag,
                                                   void* __restrict__ out) {
    __shared__ float Wfs[2560];      // Wf[c*40+o] natural layout: lanes o stride-1 -> conflict-free
    __shared__ float xsh[4][64];
    int t = threadIdx.x;
#pragma unroll
    for (int i = 0; i < 10; ++i) Wfs[i * 256 + t] = prm[P_WF + i * 256 + t];

    int wid = t >> 6, lane = t & 63;
    int v = blockIdx.x * 4 + wid;
    int rs = row_start[v], re = row_start[v + 1];
    float acc = agg_core(h_bf, as_, ad_, col, v, rs, re, lane);
    float x2 = acc + prm[P_B2 + lane];
    unsigned short u = x1_bf[(size_t)v * 64 + lane];
    float x1v = __uint_as_float(((unsigned int)u) << 16);
    xsh[wid][lane] = fmaxf(x1v, x2);   // JumpingKnowledge max
    __syncthreads();

    if (t < 160) {                     // 4 nodes x 40 outputs
        int n = t / 40, o = t - n * 40;
        float po = 0.f;
#pragma unroll
        for (int c = 0; c < 64; c += 4) {
            po = fmaf(xsh[n][c],     Wfs[c * 40 + o],       po);
            po = fmaf(xsh[n][c + 1], Wfs[(c + 1) * 40 + o], po);
            po = fmaf(xsh[n][c + 2], Wfs[(c + 2) * 40 + o], po);
            po = fmaf(xsh[n][c + 3], Wfs[(c + 3) * 40 + o], po);
        }
        float r = po + prm[P_BF + o];
        size_t idx = (size_t)(blockIdx.x * 4 + n) * 40 + o;
        if (*flag) ((float*)out)[idx] = r;
        else ((__hip_bfloat16*)out)[idx] = __float2bfloat16(r);
    }
}

extern "C" void kernel_launch(void* const* d_in, const int* in_sizes, int n_in,
                              void* d_out, int out_size, void* d_ws, size_t ws_size,
                              hipStream_t stream) {
    (void)in_sizes; (void)n_in; (void)out_size; (void)ws_size;
    const void* node_feat = d_in[0];
    const int*  edge_idx  = (const int*)d_in[1];

    char* ws = (char*)d_ws;
    size_t off = 0;
    auto alloc = [&](size_t bytes) -> void* {
        void* p = ws + off;
        off += (bytes + 255) & ~(size_t)255;
        return p;
    };
    unsigned short* h_bf  = (unsigned short*)alloc((size_t)N_NODES * 64 * 2);  // 12.8 MB
    unsigned short* x1_bf = (unsigned short*)alloc((size_t)N_NODES * 64 * 2);  // 12.8 MB
    float* as_ = (float*)alloc((size_t)N_NODES * 2 * 4);
    float* ad_ = (float*)alloc((size_t)N_NODES * 2 * 4);
    int* deg       = (int*)alloc((size_t)N_NODES * 4);
    int* row_start = (int*)alloc((size_t)(N_NODES + 1) * 4);
    int4* rank4    = (int4*)alloc((size_t)EQ4 * 16);        // 6.4 MB (32-bit ranks)
    int* col       = (int*)alloc((size_t)ETOT * 4);         // 6.8 MB
    int* bsum      = (int*)alloc((size_t)NB_SCAN * 4);
    int* boff      = (int*)alloc((size_t)NB_SCAN * 4);
    float* prm     = (float*)alloc((size_t)P_TOT * 4);
    unsigned short* fw1 = (unsigned short*)alloc(8192 * 2);
    unsigned short* fw2 = (unsigned short*)alloc(4096 * 2);
    int* flag      = (int*)alloc(256);

    detect_kernel<<<1, 64, 0, stream>>>((const unsigned short*)node_feat, flag);
    CvtArgs ca;
    const int lens[14] = {8192, 64, 64, 64, 64, 64, 64, 64, 4096, 64, 64, 64, 2560, 40};
    for (int i = 0; i < 14; ++i) { ca.ptr[i] = d_in[i + 2]; ca.len[i] = lens[i]; }
    cvt_params_kernel<<<(P_TOT + 255) / 256, 256, 0, stream>>>(ca, flag, prm);
    build_frags_kernel<<<48, 256, 0, stream>>>(prm, fw1, fw2);

    // R15/R16: fused hist(8 edges/thread) + gemm1 fat kernel.
    hipMemsetAsync(deg, 0, (size_t)N_NODES * 4, stream);
    fused_hist_gemm1_kernel<<<NB_EQ8 + NGB, 256, 0, stream>>>(
        edge_idx, deg, rank4, node_feat, fw1, prm, flag, h_bf, as_, ad_);
    scanA_kernel<<<NB_SCAN, 256, 0, stream>>>(deg, bsum);
    scanB_kernel<<<1, 512, 0, stream>>>(bsum, boff, row_start);
    scanC_kernel<<<NB_SCAN, 256, 0, stream>>>(deg, boff, row_start, col);
    scatter_kernel<<<NB_EQ4, 256, 0, stream>>>(edge_idx, rank4, row_start, col);

    agg1_kernel<<<N_NODES / 4, 256, 0, stream>>>(h_bf, as_, ad_, row_start, col,
                                                 prm + P_B1, prm + P_BNG, prm + P_BNB,
                                                 prm + P_BNM, prm + P_BNV, x1_bf);
    gemm2_kernel<<<N_NODES / 32, 128, 0, stream>>>(x1_bf, fw2, prm,
                                                   h_bf, as_, ad_);
    agg2_kernel<<<N_NODES / 4, 256, 0, stream>>>(h_bf, as_, ad_, row_start, col,
                                                 prm, x1_bf, flag, d_out);
}

// Round 14
// 333.689 us; speedup vs baseline: 1.1401x; 1.0999x over previous
//
#include <hip/hip_runtime.h>
#include <hip/hip_bf16.h>

#define N_NODES 100000
#define E_EDGES 1600000
#define ETOT    1700000   // E + N self-loops
#define EQ8     200000    // E_EDGES / 8
#define NB_EQ8  782       // ceil(EQ8 / 256)
#define NGB     1563      // gemm1 sub-grid: ceil(N / 64)
#define NBUK    196       // dst>>9 buckets (512 nodes each; last has 160)
#define F_IN    128
#define HC      64
#define OUT_C   40
#define NEG_SLOPE 0.2f
#define BN_EPS  1e-5f

// fp32 param block layout (element offsets)
#define P_W1   0
#define P_AS1  8192
#define P_AD1  8256
#define P_B1   8320
#define P_BNG  8384
#define P_BNB  8448
#define P_BNM  8512
#define P_BNV  8576
#define P_W2   8640
#define P_AS2  12736
#define P_AD2  12800
#define P_B2   12864
#define P_WF   12928
#define P_BF   15488
#define P_TOT  15528

typedef __attribute__((ext_vector_type(8))) short short8;
typedef __attribute__((ext_vector_type(4))) float floatx4;
typedef __attribute__((ext_vector_type(4))) unsigned int uintx4;

__device__ __forceinline__ unsigned short f2bf(float f) {   // RNE fp32->bf16
    unsigned int u = __float_as_uint(f);
    unsigned int r = u + 0x7FFFu + ((u >> 16) & 1u);
    return (unsigned short)(r >> 16);
}

__device__ __forceinline__ float leaky(float v) { return v > 0.f ? v : NEG_SLOPE * v; }

__device__ __forceinline__ float red64(float v) {
#pragma unroll
    for (int off = 32; off > 0; off >>= 1) v += __shfl_xor(v, off, 64);
    return v;
}
__device__ __forceinline__ float red16(float v) {
#pragma unroll
    for (int off = 8; off > 0; off >>= 1) v += __shfl_xor(v, off, 64);
    return v;
}

// ---------------- dtype detection ----------------
__global__ __launch_bounds__(64) void detect_kernel(const unsigned short* __restrict__ x,
                                                    int* __restrict__ flag) {
    int t = threadIdx.x;
    bool huge = false;
#pragma unroll
    for (int i = 0; i < 4; ++i) {
        unsigned short u = x[(t * 4 + i) * 2];
        float v = __uint_as_float(((unsigned int)u) << 16);
        if (!(fabsf(v) < 1e4f)) huge = true;
    }
    unsigned long long b = __ballot(huge);
    if (t == 0) *flag = (b != 0ull) ? 1 : 0;             // 1 => fp32 tensors
}

// ---------------- small-param conversion to fp32 ----------------
struct CvtArgs { const void* ptr[14]; int len[14]; };

__global__ __launch_bounds__(256) void cvt_params_kernel(CvtArgs a,
                                                         const int* __restrict__ flag,
                                                         float* __restrict__ dst) {
    int f = *flag;
    int i = blockIdx.x * 256 + threadIdx.x;
    if (i >= P_TOT) return;
    int k = 0, off = 0;
    while (i >= off + a.len[k]) { off += a.len[k]; ++k; }
    int j = i - off;
    float v = f ? ((const float*)a.ptr[k])[j]
                : __bfloat162float(((const __hip_bfloat16*)a.ptr[k])[j]);
    dst[i] = v;
}

// ---------------- W1/W2 -> bf16 MFMA B-fragment order ----------------
__global__ __launch_bounds__(256) void build_frags_kernel(const float* __restrict__ prm,
                                                          unsigned short* __restrict__ fw1,
                                                          unsigned short* __restrict__ fw2) {
    int i = blockIdx.x * 256 + threadIdx.x;
    if (i < 8192) {
        int j = i & 7, l = (i >> 3) & 63, q = (i >> 9) & 3, t = i >> 11;
        int k = q * 32 + (l >> 4) * 8 + j;
        int n = t * 16 + (l & 15);
        fw1[i] = f2bf(prm[P_W1 + k * 64 + n]);
    } else if (i < 12288) {
        int f = i - 8192;
        int j = f & 7, l = (f >> 3) & 63, q = (f >> 9) & 1, t = f >> 10;
        int k = q * 32 + (l >> 4) * 8 + j;
        int n = t * 16 + (l & 15);
        fw2[f] = f2bf(prm[P_W2 + k * 64 + n]);
    }
}

// ---------------- R17b: bucketed counting-sort CSR (stagger bug fixed) ----------------
// R11 decisive null: 1.6M returning device atomics cap at ~19G/s. Replace
// with LDS atomics: P1 LDS-histograms 196 coarse buckets (dst>>9); P2 scans
// bucket offsets; P3 scatters edges bucket-contiguously (LDS rank + 1 global
// atomic per block-bucket); P4 builds each bucket's 512-node CSR in LDS.
// R12 crash root-cause: stagger used blockIdx.x (up to 781) with a single
// conditional subtract -> tb up to 780 -> OOB LDS reads + OOB global atomics
// -> garbage estage indices -> wild stores. Fix: tb = t + (blockIdx.x % NBUK)
// then one conditional subtract (exact since tb < 2*NBUK).

// P1 fused with gemm1 (independent: P1 writes bkt_cnt; gemm writes h_bf/as_/ad_)
__global__ __launch_bounds__(256) void fused_hist_gemm1_kernel(
        const int* __restrict__ ei, int* __restrict__ bkt_cnt,
        const void* __restrict__ x, const unsigned short* __restrict__ fw1,
        const float* __restrict__ prm, const int* __restrict__ flag,
        unsigned short* __restrict__ h_bf, float* __restrict__ as_,
        float* __restrict__ ad_) {
    __shared__ short lx[4 * 4 * 64 * 8];   // 16 KB (gemm role); P1 reuses as cnt
    int t = threadIdx.x;
    if (blockIdx.x < NB_EQ8) {
        // -------- P1 role: LDS bucket histogram --------
        int* cnt = (int*)lx;
        if (t < NBUK) cnt[t] = 0;
        __syncthreads();
        int i8 = blockIdx.x * 256 + t;
        if (i8 < EQ8) {
            const unsigned long long* dst2 = (const unsigned long long*)(ei + E_EDGES);
            unsigned long long p0 = __builtin_nontemporal_load(&dst2[i8 * 4]);
            unsigned long long p1 = __builtin_nontemporal_load(&dst2[i8 * 4 + 1]);
            unsigned long long p2 = __builtin_nontemporal_load(&dst2[i8 * 4 + 2]);
            unsigned long long p3 = __builtin_nontemporal_load(&dst2[i8 * 4 + 3]);
            atomicAdd(&cnt[(int)(p0 & 0xFFFFFFFFull) >> 9], 1);
            atomicAdd(&cnt[(int)(p0 >> 32) >> 9], 1);
            atomicAdd(&cnt[(int)(p1 & 0xFFFFFFFFull) >> 9], 1);
            atomicAdd(&cnt[(int)(p1 >> 32) >> 9], 1);
            atomicAdd(&cnt[(int)(p2 & 0xFFFFFFFFull) >> 9], 1);
            atomicAdd(&cnt[(int)(p2 >> 32) >> 9], 1);
            atomicAdd(&cnt[(int)(p3 & 0xFFFFFFFFull) >> 9], 1);
            atomicAdd(&cnt[(int)(p3 >> 32) >> 9], 1);
        }
        __syncthreads();
        if (t < NBUK) {
            int tb = t + (int)(blockIdx.x % NBUK);          // bijective stagger
            tb -= (tb >= NBUK) ? NBUK : 0;
            int c = cnt[tb];
            if (c) atomicAdd(&bkt_cnt[tb], c);
        }
        return;
    }

    // -------- gemm1 role: h_bf[N,64] = x[N,128] @ W1, + fused alpha --------
    int f = *flag;
    int base = (blockIdx.x - NB_EQ8) * 64;

#pragma unroll
    for (int i = 0; i < 4; ++i) {
        int cid = i * 256 + t;            // 0..1023 = 64 rows x 16 col-groups
        int m = cid >> 4, c = cid & 15;
        int q = c >> 2, g = c & 3;
        int loff = (((m >> 4) * 4 + q) * 64 + g * 16 + (m & 15)) * 8;
        int srow = base + m; if (srow > N_NODES - 1) srow = N_NODES - 1;  // tail clamp
        short8 s;
        if (f) {
            const float4* p = (const float4*)((const float*)x + ((size_t)srow << 7) + (c << 3));
            float4 u0 = p[0], u1 = p[1];
            s[0] = (short)f2bf(u0.x); s[1] = (short)f2bf(u0.y);
            s[2] = (short)f2bf(u0.z); s[3] = (short)f2bf(u0.w);
            s[4] = (short)f2bf(u1.x); s[5] = (short)f2bf(u1.y);
            s[6] = (short)f2bf(u1.z); s[7] = (short)f2bf(u1.w);
        } else {
            s = *(const short8*)((const unsigned short*)x + ((size_t)srow << 7) + (c << 3));
        }
        *(short8*)&lx[loff] = s;
    }
    __syncthreads();

    int w = t >> 6, lane = t & 63;
    short8 a[4];
#pragma unroll
    for (int q = 0; q < 4; ++q) a[q] = *(short8*)&lx[((w * 4 + q) * 64 + lane) * 8];

    const short8* bw = (const short8*)fw1;
    floatx4 acc[4];
#pragma unroll
    for (int tt = 0; tt < 4; ++tt) acc[tt] = (floatx4){0.f, 0.f, 0.f, 0.f};
#pragma unroll
    for (int tt = 0; tt < 4; ++tt) {
#pragma unroll
        for (int q = 0; q < 4; ++q) {
            short8 b = bw[(tt * 4 + q) * 64 + lane];
            acc[tt] = __builtin_amdgcn_mfma_f32_16x16x32_bf16(a[q], b, acc[tt], 0, 0, 0);
        }
    }

    int cl = lane & 15, grp = lane >> 4;
#pragma unroll
    for (int tt = 0; tt < 4; ++tt) {
#pragma unroll
        for (int r = 0; r < 4; ++r) {
            int node = base + w * 16 + grp * 4 + r;
            if (node < N_NODES)
                h_bf[(size_t)node * 64 + tt * 16 + cl] = f2bf(acc[tt][r]);
        }
    }

    float as0 = prm[P_AS1 + 0  + cl], as1 = prm[P_AS1 + 16 + cl],
          as2 = prm[P_AS1 + 32 + cl], as3 = prm[P_AS1 + 48 + cl];
    float ad0 = prm[P_AD1 + 0  + cl], ad1 = prm[P_AD1 + 16 + cl],
          ad2 = prm[P_AD1 + 32 + cl], ad3 = prm[P_AD1 + 48 + cl];
#pragma unroll
    for (int r = 0; r < 4; ++r) {
        float sh0 = red16(acc[0][r] * as0 + acc[1][r] * as1);
        float sh1 = red16(acc[2][r] * as2 + acc[3][r] * as3);
        float dh0 = red16(acc[0][r] * ad0 + acc[1][r] * ad1);
        float dh1 = red16(acc[2][r] * ad2 + acc[3][r] * ad3);
        int node = base + w * 16 + grp * 4 + r;
        if (cl == 0 && node < N_NODES) {
            as_[node * 2] = sh0;  as_[node * 2 + 1] = sh1;
            ad_[node * 2] = dh0;  ad_[node * 2 + 1] = dh1;
        }
    }
}

// P2: scan bucket counts -> boff[NBUK+1], bcur; set row_start[N]
__global__ __launch_bounds__(256) void bucket_scan_kernel(const int* __restrict__ bkt_cnt,
                                                          int* __restrict__ boff,
                                                          int* __restrict__ bcur,
                                                          int* __restrict__ row_start) {
    __shared__ int sm[256];
    int t = threadIdx.x;
    int v = (t < NBUK) ? bkt_cnt[t] : 0;
    sm[t] = v;
    __syncthreads();
    for (int off = 1; off < 256; off <<= 1) {
        int o = (t >= off) ? sm[t - off] : 0;
        __syncthreads();
        sm[t] += o;
        __syncthreads();
    }
    if (t < NBUK) { int e = sm[t] - v; boff[t] = e; bcur[t] = e; }
    if (t == NBUK - 1) boff[NBUK] = sm[t];           // == E_EDGES
    if (t == 0) row_start[N_NODES] = ETOT;
}

// P3: bucket scatter -- LDS rank within block + 1 global atomic per (block,bucket)
__global__ __launch_bounds__(256) void bucket_scatter_kernel(const int* __restrict__ ei,
                                                             int* __restrict__ bcur,
                                                             unsigned long long* __restrict__ estage) {
    __shared__ int cnt[NBUK];
    __shared__ int base[NBUK];
    int t = threadIdx.x;
    if (t < NBUK) cnt[t] = 0;
    __syncthreads();
    int i8 = blockIdx.x * 256 + t;
    bool valid = i8 < EQ8;
    int d[8], s[8], rl[8];
    if (valid) {
        const unsigned long long* dst2 = (const unsigned long long*)(ei + E_EDGES);
        const unsigned long long* src2 = (const unsigned long long*)ei;
        unsigned long long p0 = __builtin_nontemporal_load(&dst2[i8 * 4]);
        unsigned long long p1 = __builtin_nontemporal_load(&dst2[i8 * 4 + 1]);
        unsigned long long p2 = __builtin_nontemporal_load(&dst2[i8 * 4 + 2]);
        unsigned long long p3 = __builtin_nontemporal_load(&dst2[i8 * 4 + 3]);
        unsigned long long q0 = __builtin_nontemporal_load(&src2[i8 * 4]);
        unsigned long long q1 = __builtin_nontemporal_load(&src2[i8 * 4 + 1]);
        unsigned long long q2 = __builtin_nontemporal_load(&src2[i8 * 4 + 2]);
        unsigned long long q3 = __builtin_nontemporal_load(&src2[i8 * 4 + 3]);
        d[0] = (int)(p0 & 0xFFFFFFFFull); d[1] = (int)(p0 >> 32);
        d[2] = (int)(p1 & 0xFFFFFFFFull); d[3] = (int)(p1 >> 32);
        d[4] = (int)(p2 & 0xFFFFFFFFull); d[5] = (int)(p2 >> 32);
        d[6] = (int)(p3 & 0xFFFFFFFFull); d[7] = (int)(p3 >> 32);
        s[0] = (int)(q0 & 0xFFFFFFFFull); s[1] = (int)(q0 >> 32);
        s[2] = (int)(q1 & 0xFFFFFFFFull); s[3] = (int)(q1 >> 32);
        s[4] = (int)(q2 & 0xFFFFFFFFull); s[5] = (int)(q2 >> 32);
        s[6] = (int)(q3 & 0xFFFFFFFFull); s[7] = (int)(q3 >> 32);
#pragma unroll
        for (int k = 0; k < 8; ++k) rl[k] = atomicAdd(&cnt[d[k] >> 9], 1);
    }
    __syncthreads();
    if (t < NBUK) {
        int tb = t + (int)(blockIdx.x % NBUK);              // bijective stagger
        tb -= (tb >= NBUK) ? NBUK : 0;
        int c = cnt[tb];
        base[tb] = c ? atomicAdd(&bcur[tb], c) : 0;
    }
    __syncthreads();
    if (valid) {
#pragma unroll
        for (int k = 0; k < 8; ++k) {
            int buk = d[k] >> 9;
            estage[base[buk] + rl[k]] =
                (unsigned long long)(unsigned int)s[k] |
                ((unsigned long long)(unsigned int)d[k] << 32);
        }
    }
}

// P4: per-bucket CSR build, all in LDS (hist -> scan -> rank scatter)
__global__ __launch_bounds__(256) void bucket_csr_kernel(const unsigned long long* __restrict__ estage,
                                                         const int* __restrict__ boff,
                                                         int* __restrict__ row_start,
                                                         int* __restrict__ col) {
    __shared__ int ldeg[512];
    __shared__ int sA[512], sB[512];
    __shared__ int exq[512];
    int b = blockIdx.x, t = threadIdx.x;
    int nbase = b << 9;
    int nb = N_NODES - nbase; if (nb > 512) nb = 512;
    int e0 = boff[b], e1 = boff[b + 1];
    int rb = e0 + nbase;                   // global CSR base for this bucket
    ldeg[t] = 0; ldeg[t + 256] = 0;
    __syncthreads();
    for (int e = e0 + t; e < e1; e += 256) {
        int dl = (int)(estage[e] >> 32) - nbase;
        atomicAdd(&ldeg[dl], 1);
    }
    __syncthreads();
    int v0 = (t < nb) ? ldeg[t] + 1 : 0;           // +1 self-loop
    int v1 = (t + 256 < nb) ? ldeg[t + 256] + 1 : 0;
    sA[t] = v0; sA[t + 256] = v1;
    __syncthreads();
    int* A = sA; int* Bp = sB;
    for (int off = 1; off < 512; off <<= 1) {      // Hillis-Steele inclusive
        int a0 = A[t] + ((t >= off) ? A[t - off] : 0);
        int a1 = A[t + 256] + ((t + 256 >= off) ? A[t + 256 - off] : 0);
        Bp[t] = a0; Bp[t + 256] = a1;
        __syncthreads();
        int* tmp = A; A = Bp; Bp = tmp;
    }
    exq[t] = A[t] - v0;                            // exclusive scan
    exq[t + 256] = A[t + 256] - v1;
    __syncthreads();
    if (t < nb) { int rsv = rb + exq[t]; row_start[nbase + t] = rsv; col[rsv] = nbase + t; }
    if (t + 256 < nb) { int rsv = rb + exq[t + 256]; row_start[nbase + t + 256] = rsv; col[rsv] = nbase + t + 256; }
    ldeg[t] = 0; ldeg[t + 256] = 0;                // reuse as rank counters
    __syncthreads();
    for (int e = e0 + t; e < e1; e += 256) {
        unsigned long long p = estage[e];
        int s = (int)(p & 0xFFFFFFFFull);
        int dl = (int)(p >> 32) - nbase;
        int r = atomicAdd(&ldeg[dl], 1);
        col[rb + exq[dl] + 1 + r] = s;
    }
}

// ---------------- MFMA GEMM 2: h_bf = x1_bf[N,64] @ W2, + fused alpha ----------------
__global__ __launch_bounds__(128) void gemm2_kernel(const unsigned short* __restrict__ x1_bf,
                                                    const unsigned short* __restrict__ fw2,
                                                    const float* __restrict__ prm,
                                                    unsigned short* __restrict__ h_bf,
                                                    float* __restrict__ as_,
                                                    float* __restrict__ ad_) {
    __shared__ short lx[2 * 2 * 64 * 8];   // 4 KB
    int t = threadIdx.x;
    int base = blockIdx.x * 32;

#pragma unroll
    for (int i = 0; i < 2; ++i) {
        int cid = i * 128 + t;
        int m = cid >> 3, c = cid & 7;
        int q = c >> 2, g = c & 3;
        int loff = (((m >> 4) * 2 + q) * 64 + g * 16 + (m & 15)) * 8;
        short8 s = *(const short8*)(x1_bf + ((size_t)(base + m) << 6) + (c << 3));
        *(short8*)&lx[loff] = s;
    }
    __syncthreads();

    int w = t >> 6, lane = t & 63;
    short8 a[2];
#pragma unroll
    for (int q = 0; q < 2; ++q) a[q] = *(short8*)&lx[((w * 2 + q) * 64 + lane) * 8];

    const short8* bw = (const short8*)fw2;
    floatx4 acc[4];
#pragma unroll
    for (int tt = 0; tt < 4; ++tt) acc[tt] = (floatx4){0.f, 0.f, 0.f, 0.f};
#pragma unroll
    for (int tt = 0; tt < 4; ++tt) {
#pragma unroll
        for (int q = 0; q < 2; ++q) {
            short8 b = bw[(tt * 2 + q) * 64 + lane];
            acc[tt] = __builtin_amdgcn_mfma_f32_16x16x32_bf16(a[q], b, acc[tt], 0, 0, 0);
        }
    }

    int cl = lane & 15, grp = lane >> 4;
#pragma unroll
    for (int tt = 0; tt < 4; ++tt) {
#pragma unroll
        for (int r = 0; r < 4; ++r) {
            int node = base + w * 16 + grp * 4 + r;
            h_bf[(size_t)node * 64 + tt * 16 + cl] = f2bf(acc[tt][r]);
        }
    }

    float as0 = prm[P_AS2 + 0  + cl], as1 = prm[P_AS2 + 16 + cl],
          as2 = prm[P_AS2 + 32 + cl], as3 = prm[P_AS2 + 48 + cl];
    float ad0 = prm[P_AD2 + 0  + cl], ad1 = prm[P_AD2 + 16 + cl],
          ad2 = prm[P_AD2 + 32 + cl], ad3 = prm[P_AD2 + 48 + cl];
#pragma unroll
    for (int r = 0; r < 4; ++r) {
        float sh0 = red16(acc[0][r] * as0 + acc[1][r] * as1);
        float sh1 = red16(acc[2][r] * as2 + acc[3][r] * as3);
        float dh0 = red16(acc[0][r] * ad0 + acc[1][r] * ad1);
        float dh1 = red16(acc[2][r] * ad2 + acc[3][r] * ad3);
        if (cl == 0) {
            int node = base + w * 16 + grp * 4 + r;
            as_[node * 2] = sh0;  as_[node * 2 + 1] = sh1;
            ad_[node * 2] = dh0;  ad_[node * 2 + 1] = dh1;
        }
    }
}

// halving slot-reduction: lane ends with channel k=(lane&7) summed over its
// octet's 8 slots. 7 shfl + 14 sel + 7 add. All shuffles convergent.
__device__ __forceinline__ float slot_reduce(float acc[8], int lane) {
    int slot = lane & 7;
    bool b2 = (slot & 4) != 0;
#pragma unroll
    for (int q = 0; q < 4; ++q) {
        float send = b2 ? acc[q] : acc[q + 4];
        float recv = __shfl_xor(send, 4, 64);
        acc[q] = (b2 ? acc[q + 4] : acc[q]) + recv;
    }
    bool b1 = (slot & 2) != 0;
#pragma unroll
    for (int q = 0; q < 2; ++q) {
        float send = b1 ? acc[q] : acc[q + 2];
        float recv = __shfl_xor(send, 2, 64);
        acc[q] = (b1 ? acc[q + 2] : acc[q]) + recv;
    }
    bool b0 = (slot & 1) != 0;
    float send = b0 ? acc[0] : acc[1];
    float recv = __shfl_xor(send, 1, 64);
    return (b0 ? acc[1] : acc[0]) + recv;
}

// ---------------- aggregation round batch (R14 pin kept, harmless) ----------------
template<int NK>
__device__ __forceinline__ void agg_rounds(const unsigned short* __restrict__ hb,
                                           const float* __restrict__ as_,
                                           const int* __restrict__ col,
                                           int rs, int koff, int last,
                                           int slot, int hi, float advh,
                                           float acc[8], float& sw) {
    int ce[NK]; float av[NK]; uintx4 dv[NK];
#pragma unroll
    for (int k = 0; k < NK; ++k) {
        int e = rs + koff + k * 8 + slot;
        ce[k] = col[e < last ? e : last];     // clamped: always valid
    }
#pragma unroll
    for (int k = 0; k < NK; ++k)
        dv[k] = *(const uintx4*)(hb + ((size_t)ce[k] << 6));
#pragma unroll
    for (int k = 0; k < NK; ++k)
        av[k] = as_[ce[k] * 2 + hi];

    if constexpr (NK == 1) {
        asm volatile("" : "+v"(dv[0]), "+v"(av[0]));
    } else if constexpr (NK == 2) {
        asm volatile("" : "+v"(dv[0]), "+v"(dv[1]), "+v"(av[0]), "+v"(av[1]));
    } else if constexpr (NK == 3) {
        asm volatile("" : "+v"(dv[0]), "+v"(dv[1]), "+v"(dv[2]),
                          "+v"(av[0]), "+v"(av[1]), "+v"(av[2]));
    } else {
        asm volatile("" : "+v"(dv[0]), "+v"(dv[1]), "+v"(dv[2]), "+v"(dv[3]),
                          "+v"(av[0]), "+v"(av[1]), "+v"(av[2]), "+v"(av[3]));
    }

#pragma unroll
    for (int k = 0; k < NK; ++k) {
        int e = rs + koff + k * 8 + slot;
        float w = (e <= last) ? __expf(leaky(av[k] + advh)) : 0.f;
        sw += w;
#pragma unroll
        for (int q = 0; q < 4; ++q) {
            unsigned int dw = dv[k][q];
            acc[2 * q]     = fmaf(w, __uint_as_float(dw << 16),         acc[2 * q]);
            acc[2 * q + 1] = fmaf(w, __uint_as_float(dw & 0xFFFF0000u), acc[2 * q + 1]);
        }
    }
}

// ---------------- aggregation core, slot-parallel, degree-adaptive ----------------
// R8: agg bound by the structural L2-fill floor (8 XCDs x 12.8MB h_bf =
// constant 105MB FETCH at ~1.75TB/s). R10/R13/R14 structure kept.
__device__ __forceinline__ float agg_core(const unsigned short* __restrict__ h_bf,
                                          const float* __restrict__ as_,
                                          const float* __restrict__ ad_,
                                          const int* __restrict__ col,
                                          int v, int rs, int re, int lane) {
    int deg  = re - rs;
    int slot = lane & 7;
    int cg   = lane >> 3;        // channel group: my 8 channels = cg*8..cg*8+7
    int hi   = cg >> 2;          // head owning my channels
    if (deg <= 64) {
        float advh = ad_[v * 2 + hi];
        const unsigned short* hb = h_bf + (cg << 3);
        int last = re - 1;       // >= rs always (self-loop)
        float acc[8] = {0.f,0.f,0.f,0.f,0.f,0.f,0.f,0.f};
        float sw = 0.f;

        if (deg <= 8) {
            agg_rounds<1>(hb, as_, col, rs, 0, last, slot, hi, advh, acc, sw);
        } else if (deg <= 16) {
            agg_rounds<2>(hb, as_, col, rs, 0, last, slot, hi, advh, acc, sw);
        } else if (deg <= 24) {
            agg_rounds<3>(hb, as_, col, rs, 0, last, slot, hi, advh, acc, sw);
        } else {
            agg_rounds<4>(hb, as_, col, rs, 0, last, slot, hi, advh, acc, sw);
            if (deg > 32)
                agg_rounds<4>(hb, as_, col, rs, 32, last, slot, hi, advh, acc, sw);
        }

        // denominator: sum over the octet's 8 slots (3 convergent shuffles)
        sw += __shfl_xor(sw, 1, 64);
        sw += __shfl_xor(sw, 2, 64);
        sw += __shfl_xor(sw, 4, 64);
        float rdh = 1.f / (sw + 1e-16f);

        return slot_reduce(acc, lane) * rdh;
    } else {
        int head = lane >> 5;
        float adv0 = ad_[v * 2], adv1 = ad_[v * 2 + 1];
        float advh = head ? adv1 : adv0;
        float s0 = 0.f, s1 = 0.f;
        for (int e = rs + lane; e < re; e += 64) {
            int s = col[e];
            float2 av = *(const float2*)&as_[s * 2];
            s0 += __expf(leaky(av.x + adv0));
            s1 += __expf(leaky(av.y + adv1));
        }
        s0 = red64(s0); s1 = red64(s1);
        float rdh = 1.f / ((head ? s1 : s0) + 1e-16f);
        float a0 = 0.f;
        for (int e = rs; e < re; ++e) {
            int s = col[e];
            float w = __expf(leaky(as_[s * 2 + head] + advh));
            unsigned short u = h_bf[(size_t)s * 64 + lane];
            a0 = fmaf(w, __uint_as_float(((unsigned int)u) << 16), a0);
        }
        return a0 * rdh;
    }
}

// ---------------- aggregation layer 1 (+bias, BN eval, ELU) -> x1_bf ----------------
__global__ __launch_bounds__(256, 6) void agg1_kernel(const unsigned short* __restrict__ h_bf,
                                                   const float* __restrict__ as_,
                                                   const float* __restrict__ ad_,
                                                   const int* __restrict__ row_start,
                                                   const int* __restrict__ col,
                                                   const float* __restrict__ bias,
                                                   const float* __restrict__ bn_g,
                                                   const float* __restrict__ bn_b,
                                                   const float* __restrict__ bn_m,
                                                   const float* __restrict__ bn_v,
                                                   unsigned short* __restrict__ x1_bf) {
    int t = threadIdx.x, wid = t >> 6, lane = t & 63;
    int v = blockIdx.x * 4 + wid;
    int rs = row_start[v], re = row_start[v + 1];
    float acc = agg_core(h_bf, as_, ad_, col, v, rs, re, lane);
    float r = acc + bias[lane];
    float scale = bn_g[lane] * rsqrtf(bn_v[lane] + BN_EPS);
    r = (r - bn_m[lane]) * scale + bn_b[lane];
    r = r > 0.f ? r : expm1f(r);   // ELU
    x1_bf[(size_t)v * 64 + lane] = f2bf(r);
}

// ---------------- agg layer 2 + JK max + fused projection -> out [N,40] ----------------
__global__ __launch_bounds__(256, 6) void agg2_kernel(const unsigned short* __restrict__ h_bf,
                                                   const float* __restrict__ as_,
                                                   const float* __restrict__ ad_,
                                                   const int* __restrict__ row_start,
                                                   const int* __restrict__ col,
                                                   const float* __restrict__ prm,
                                                   const unsigned short* __restrict__ x1_bf,
                                                   const int* __restrict__ flag,
                                                   void* __restrict__ out) {
    __shared__ float Wfs[2560];      // Wf[c*40+o] natural layout: lanes o stride-1 -> conflict-free
    __shared__ float xsh[4][64];
    int t = threadIdx.x;
#pragma unroll
    for (int i = 0; i < 10; ++i) Wfs[i * 256 + t] = prm[P_WF + i * 256 + t];

    int wid = t >> 6, lane = t & 63;
    int v = blockIdx.x * 4 + wid;
    int rs = row_start[v], re = row_start[v + 1];
    float acc = agg_core(h_bf, as_, ad_, col, v, rs, re, lane);
    float x2 = acc + prm[P_B2 + lane];
    unsigned short u = x1_bf[(size_t)v * 64 + lane];
    float x1v = __uint_as_float(((unsigned int)u) << 16);
    xsh[wid][lane] = fmaxf(x1v, x2);   // JumpingKnowledge max
    __syncthreads();

    if (t < 160) {                     // 4 nodes x 40 outputs
        int n = t / 40, o = t - n * 40;
        float po = 0.f;
#pragma unroll
        for (int c = 0; c < 64; c += 4) {
            po = fmaf(xsh[n][c],     Wfs[c * 40 + o],       po);
            po = fmaf(xsh[n][c + 1], Wfs[(c + 1) * 40 + o], po);
            po = fmaf(xsh[n][c + 2], Wfs[(c + 2) * 40 + o], po);
            po = fmaf(xsh[n][c + 3], Wfs[(c + 3) * 40 + o], po);
        }
        float r = po + prm[P_BF + o];
        size_t idx = (size_t)(blockIdx.x * 4 + n) * 40 + o;
        if (*flag) ((float*)out)[idx] = r;
        else ((__hip_bfloat16*)out)[idx] = __float2bfloat16(r);
    }
}

extern "C" void kernel_launch(void* const* d_in, const int* in_sizes, int n_in,
                              void* d_out, int out_size, void* d_ws, size_t ws_size,
                              hipStream_t stream) {
    (void)in_sizes; (void)n_in; (void)out_size; (void)ws_size;
    const void* node_feat = d_in[0];
    const int*  edge_idx  = (const int*)d_in[1];

    char* ws = (char*)d_ws;
    size_t off = 0;
    auto alloc = [&](size_t bytes) -> void* {
        void* p = ws + off;
        off += (bytes + 255) & ~(size_t)255;
        return p;
    };
    unsigned short* h_bf  = (unsigned short*)alloc((size_t)N_NODES * 64 * 2);  // 12.8 MB
    unsigned short* x1_bf = (unsigned short*)alloc((size_t)N_NODES * 64 * 2);  // 12.8 MB
    float* as_ = (float*)alloc((size_t)N_NODES * 2 * 4);
    float* ad_ = (float*)alloc((size_t)N_NODES * 2 * 4);
    int* row_start = (int*)alloc((size_t)(N_NODES + 1) * 4);
    unsigned long long* estage = (unsigned long long*)alloc((size_t)E_EDGES * 8); // 12.8 MB
    int* col       = (int*)alloc((size_t)ETOT * 4);         // 6.8 MB
    int* bkt_cnt   = (int*)alloc((size_t)NBUK * 4);
    int* bkt_off   = (int*)alloc((size_t)(NBUK + 1) * 4);
    int* bkt_cur   = (int*)alloc((size_t)NBUK * 4);
    float* prm     = (float*)alloc((size_t)P_TOT * 4);
    unsigned short* fw1 = (unsigned short*)alloc(8192 * 2);
    unsigned short* fw2 = (unsigned short*)alloc(4096 * 2);
    int* flag      = (int*)alloc(256);

    detect_kernel<<<1, 64, 0, stream>>>((const unsigned short*)node_feat, flag);
    CvtArgs ca;
    const int lens[14] = {8192, 64, 64, 64, 64, 64, 64, 64, 4096, 64, 64, 64, 2560, 40};
    for (int i = 0; i < 14; ++i) { ca.ptr[i] = d_in[i + 2]; ca.len[i] = lens[i]; }
    cvt_params_kernel<<<(P_TOT + 255) / 256, 256, 0, stream>>>(ca, flag, prm);
    build_frags_kernel<<<48, 256, 0, stream>>>(prm, fw1, fw2);

    // R17b bucketed counting-sort CSR: P1(fused w/ gemm1) -> P2 -> P3 -> P4
    hipMemsetAsync(bkt_cnt, 0, (size_t)NBUK * 4, stream);
    fused_hist_gemm1_kernel<<<NB_EQ8 + NGB, 256, 0, stream>>>(
        edge_idx, bkt_cnt, node_feat, fw1, prm, flag, h_bf, as_, ad_);
    bucket_scan_kernel<<<1, 256, 0, stream>>>(bkt_cnt, bkt_off, bkt_cur, row_start);
    bucket_scatter_kernel<<<NB_EQ8, 256, 0, stream>>>(edge_idx, bkt_cur, estage);
    bucket_csr_kernel<<<NBUK, 256, 0, stream>>>(estage, bkt_off, row_start, col);

    agg1_kernel<<<N_NODES / 4, 256, 0, stream>>>(h_bf, as_, ad_, row_start, col,
                                                 prm + P_B1, prm + P_BNG, prm + P_BNB,
                                                 prm + P_BNM, prm + P_BNV, x1_bf);
    gemm2_kernel<<<N_NODES / 32, 128, 0, stream>>>(x1_bf, fw2, prm,
                                                   h_bf, as_, ad_);
    agg2_kernel<<<N_NODES / 4, 256, 0, stream>>>(h_bf, as_, ad_, row_start, col,
                                                 prm, x1_bf, flag, d_out);
}